// Round 1
// baseline (487.491 us; speedup 1.0000x reference)
//
#include <hip/hip_runtime.h>
#include <math.h>

#define WAVE 64

__device__ __forceinline__ float warpReduceSum(float v){
#pragma unroll
    for (int off = 32; off > 0; off >>= 1) v += __shfl_down(v, off);
    return v;
}
__device__ __forceinline__ float warpReduceMax(float v){
#pragma unroll
    for (int off = 32; off > 0; off >>= 1) v = fmaxf(v, __shfl_down(v, off));
    return v;
}

// block of 256 threads (4 waves); scratch must hold >=4 floats
__device__ float blockSum256(float v, float* s4){
    v = warpReduceSum(v);
    int w = threadIdx.x >> 6;
    __syncthreads();
    if ((threadIdx.x & 63) == 0) s4[w] = v;
    __syncthreads();
    return s4[0] + s4[1] + s4[2] + s4[3];
}
__device__ float blockMax256(float v, float* s4){
    v = warpReduceMax(v);
    int w = threadIdx.x >> 6;
    __syncthreads();
    if ((threadIdx.x & 63) == 0) s4[w] = v;
    __syncthreads();
    return fmaxf(fmaxf(s4[0], s4[1]), fmaxf(s4[2], s4[3]));
}

// ---------------------------------------------------------------------------
// K1: prompt self-attention (batch independent) + Qc + Qk = Qc @ wk_w^T, qkb
// single block, 256 threads
// ---------------------------------------------------------------------------
__global__ __launch_bounds__(256) void k_prep(
    const float* __restrict__ prompts,
    const float* __restrict__ qw, const float* __restrict__ qb,
    const float* __restrict__ kw, const float* __restrict__ kb,
    const float* __restrict__ vw, const float* __restrict__ vb,
    const float* __restrict__ lns, const float* __restrict__ lnb,
    const float* __restrict__ wqw, const float* __restrict__ wqb,
    const float* __restrict__ wkw, const float* __restrict__ wkb,
    float* __restrict__ P1g, float* __restrict__ Qkg, float* __restrict__ qkbg)
{
    __shared__ float Pl[1280], Ql[1280], Kl[1280], Vl[1280], Sl[25], s4[4];
    int t = threadIdx.x;
    for (int i = t; i < 1280; i += 256) Pl[i] = prompts[i];
    __syncthreads();
    // Q,K,V = P@W + b  (thread t owns output column t)
    for (int n = 0; n < 5; n++){
        float aq = qb[t], ak = kb[t], av = vb[t];
        for (int c = 0; c < 256; c++){
            float p = Pl[n*256 + c];
            aq += p * qw[c*256 + t];
            ak += p * kw[c*256 + t];
            av += p * vw[c*256 + t];
        }
        Ql[n*256 + t] = aq; Kl[n*256 + t] = ak; Vl[n*256 + t] = av;
    }
    __syncthreads();
    // 5x5 scores
    if (t < 25){
        int n = t / 5, m = t % 5;
        float s = 0.f;
        for (int c = 0; c < 256; c++) s += Ql[n*256 + c] * Kl[m*256 + c];
        Sl[t] = s * 0.0625f;
    }
    __syncthreads();
    if (t < 5){
        float mx = -1e30f;
        for (int m = 0; m < 5; m++) mx = fmaxf(mx, Sl[t*5 + m]);
        float e[5], sm = 0.f;
        for (int m = 0; m < 5; m++){ e[m] = expf(Sl[t*5 + m] - mx); sm += e[m]; }
        for (int m = 0; m < 5; m++) Sl[t*5 + m] = e[m] / sm;
    }
    __syncthreads();
    float x[5];
    for (int n = 0; n < 5; n++){
        float s = 0.f;
        for (int m = 0; m < 5; m++) s += Sl[n*5 + m] * Vl[m*256 + t];
        x[n] = Pl[n*256 + t] + s;
    }
    // LN rows -> P1 (reuse Pl)
    for (int n = 0; n < 5; n++){
        float sum  = blockSum256(x[n], s4);
        float mean = sum * (1.0f/256.0f);
        float d    = x[n] - mean;
        float sq   = blockSum256(d*d, s4);
        float rstd = rsqrtf(sq * (1.0f/256.0f) + 1e-5f);
        float y = d * rstd * lns[t] + lnb[t];
        Pl[n*256 + t] = y;
        P1g[n*256 + t] = y;
    }
    __syncthreads();
    // Qc = P1 @ wq_w + wq_b   (reuse Ql)
    for (int n = 0; n < 5; n++){
        float a = wqb[t];
        for (int c = 0; c < 256; c++) a += Pl[n*256 + c] * wqw[c*256 + t];
        Ql[n*256 + t] = a;
    }
    __syncthreads();
    // Qk[n][t] = sum_c' Qc[n][c'] * wk_w[t][c']   (fold K-projection into Q side)
    for (int n = 0; n < 5; n++){
        float a = 0.f;
        for (int c = 0; c < 256; c++) a += Ql[n*256 + c] * wkw[t*256 + c];
        Qkg[n*256 + t] = a;
    }
    if (t < 5){
        float a = 0.f;
        for (int c = 0; c < 256; c++) a += Ql[t*256 + c] * wkb[c];
        qkbg[t] = a;
    }
}

// ---------------------------------------------------------------------------
// K2: logits[b,n,m] = scale * (Qk[n,:] . Fd[b,:,m] + qkb[n])
// grid (HW/256, B), 256 threads, thread -> one pixel m
// ---------------------------------------------------------------------------
__global__ __launch_bounds__(256) void k_logits(
    const float* __restrict__ Fd, const float* __restrict__ Qk,
    const float* __restrict__ qkb, float* __restrict__ logits)
{
    __shared__ float qk[1280];
    __shared__ float qb5[5];
    int t = threadIdx.x;
    for (int i = t; i < 1280; i += 256) qk[i] = Qk[i];
    if (t < 5) qb5[t] = qkb[t];
    __syncthreads();
    int b = blockIdx.y;
    int m = blockIdx.x * 256 + t;
    const float* fp = Fd + ((size_t)b * 256) * 4096 + m;
    float a0 = qb5[0], a1 = qb5[1], a2 = qb5[2], a3 = qb5[3], a4 = qb5[4];
#pragma unroll 4
    for (int c = 0; c < 256; c++){
        float f = fp[(size_t)c * 4096];
        a0 += qk[c]        * f;
        a1 += qk[256 + c]  * f;
        a2 += qk[512 + c]  * f;
        a3 += qk[768 + c]  * f;
        a4 += qk[1024 + c] * f;
    }
    float* lp = logits + ((size_t)b * 5) * 4096 + m;
    lp[0]     = a0 * 0.0625f;
    lp[4096]  = a1 * 0.0625f;
    lp[8192]  = a2 * 0.0625f;
    lp[12288] = a3 * 0.0625f;
    lp[16384] = a4 * 0.0625f;
}

// ---------------------------------------------------------------------------
// K3: row softmax over HW: M = softmax(logits, axis=-1). 80 blocks (b*5+n).
// ---------------------------------------------------------------------------
__global__ __launch_bounds__(256) void k_softmax(
    const float* __restrict__ logits, float* __restrict__ Mg)
{
    __shared__ float s4[4];
    int r = blockIdx.x, t = threadIdx.x;
    const float* L = logits + (size_t)r * 4096;
    float v[16];
    float mx = -1e30f;
#pragma unroll
    for (int k = 0; k < 16; k++){ v[k] = L[t + k*256]; mx = fmaxf(mx, v[k]); }
    mx = blockMax256(mx, s4);
    float s = 0.f;
#pragma unroll
    for (int k = 0; k < 16; k++){ v[k] = expf(v[k] - mx); s += v[k]; }
    s = blockSum256(s, s4);
    float inv = 1.0f / s;
    float* Mp = Mg + (size_t)r * 4096;
#pragma unroll
    for (int k = 0; k < 16; k++) Mp[t + k*256] = v[k] * inv;
}

// ---------------------------------------------------------------------------
// K4: A[b,n,c] = sum_m M[b,n,m] * Fd[b,c,m]   grid (C, B), 256 threads
// ---------------------------------------------------------------------------
__global__ __launch_bounds__(256) void k_A(
    const float* __restrict__ Fd, const float* __restrict__ Mg,
    float* __restrict__ A)
{
    __shared__ float s4[4];
    int c = blockIdx.x, b = blockIdx.y, t = threadIdx.x;
    const float* fp = Fd + ((size_t)b * 256 + c) * 4096;
    const float* Mp = Mg + (size_t)b * 5 * 4096;
    float acc[5] = {0,0,0,0,0};
    for (int k = 0; k < 16; k++){
        int m = t + k*256;
        float f = fp[m];
#pragma unroll
        for (int n = 0; n < 5; n++) acc[n] += Mp[n*4096 + m] * f;
    }
    for (int n = 0; n < 5; n++){
        float s = blockSum256(acc[n], s4);
        if (t == 0) A[((size_t)b*5 + n)*256 + c] = s;
    }
}

// ---------------------------------------------------------------------------
// K5: per-batch Sinkhorn (log-domain) + BCE accumulation.
// 16 blocks x 1024 threads. log_K kept in registers (thread t owns columns
// m = t + k*1024, k=0..3, for all 5 rows). lv[4096] in LDS.
// ---------------------------------------------------------------------------
__global__ __launch_bounds__(1024) void k_sinkhorn(
    const float* __restrict__ logits, const float* __restrict__ Mg,
    float* __restrict__ out_l)
{
    __shared__ float lv[4096];
    __shared__ float redm[80], reds[80];   // 16 waves x 5 rows
    __shared__ float nl[5];
    int b = blockIdx.x, t = threadIdx.x;
    int w = t >> 6, lane = t & 63;
    const float* Lb = logits + (size_t)b * 5 * 4096;
    float lk[5][4];
#pragma unroll
    for (int n = 0; n < 5; n++)
#pragma unroll
        for (int k = 0; k < 4; k++)
            lk[n][k] = Lb[n*4096 + t + k*1024] / 0.05f;   // log_K = M / EPS
#pragma unroll
    for (int k = 0; k < 4; k++) lv[t + k*1024] = 0.0f;
    float lu[5] = {0,0,0,0,0};
    const float log_mu = logf(0.2f + 1e-8f);
    const float log_nu = logf((1.0f/4096.0f) + 1e-8f);
    __syncthreads();

    float diff = 1e30f;
    for (int it = 0; it < 100; ++it){
        if (diff < 1e-4f) break;
        float lvk[4];
#pragma unroll
        for (int k = 0; k < 4; k++) lvk[k] = lv[t + k*1024];
        // --- row logsumexp over m (4096) ---
#pragma unroll
        for (int n = 0; n < 5; n++){
            float v0 = lk[n][0] + lvk[0], v1 = lk[n][1] + lvk[1];
            float v2 = lk[n][2] + lvk[2], v3 = lk[n][3] + lvk[3];
            float lm = fmaxf(fmaxf(v0, v1), fmaxf(v2, v3));
            float ps = expf(v0-lm) + expf(v1-lm) + expf(v2-lm) + expf(v3-lm);
            float wm = lm;
#pragma unroll
            for (int off = 1; off < 64; off <<= 1) wm = fmaxf(wm, __shfl_xor(wm, off));
            float contrib = ps * expf(lm - wm);
#pragma unroll
            for (int off = 1; off < 64; off <<= 1) contrib += __shfl_xor(contrib, off);
            if (lane == 0){ redm[w*5 + n] = wm; reds[w*5 + n] = contrib; }
        }
        __syncthreads();
        if (t < 5){
            float gm = -1e30f;
            for (int i = 0; i < 16; i++) gm = fmaxf(gm, redm[i*5 + t]);
            float gs = 0.f;
            for (int i = 0; i < 16; i++) gs += reds[i*5 + t] * expf(redm[i*5 + t] - gm);
            nl[t] = log_mu - (gm + logf(gs));
        }
        __syncthreads();
        float nlr[5], nd = 0.f;
#pragma unroll
        for (int n = 0; n < 5; n++){
            nlr[n] = nl[n];
            nd = fmaxf(nd, fabsf(nlr[n] - lu[n]));
            lu[n] = nlr[n];
        }
        diff = nd;
        // --- column logsumexp over n (5), fully register-local ---
#pragma unroll
        for (int k = 0; k < 4; k++){
            float x0 = lk[0][k] + nlr[0], x1 = lk[1][k] + nlr[1];
            float x2 = lk[2][k] + nlr[2], x3 = lk[3][k] + nlr[3];
            float x4 = lk[4][k] + nlr[4];
            float cm = fmaxf(fmaxf(fmaxf(x0, x1), fmaxf(x2, x3)), x4);
            float cs = expf(x0-cm) + expf(x1-cm) + expf(x2-cm) + expf(x3-cm) + expf(x4-cm);
            lv[t + k*1024] = log_nu - (cm + logf(cs));
        }
        __syncthreads();
    }
    // --- BCE(T, M) ---
    const float* Mp = Mg + (size_t)b * 5 * 4096;
    float acc = 0.f;
#pragma unroll
    for (int n = 0; n < 5; n++){
#pragma unroll
        for (int k = 0; k < 4; k++){
            int m = t + k*1024;
            float lT = lu[n] + lk[n][k] + lv[m];
            float T  = fminf(expf(lT), 1.0f);
            float Mv = Mp[n*4096 + m];
            float Mc = fminf(fmaxf(Mv, 1e-6f), 1.0f - 1e-6f);
            acc -= T * logf(Mc) + (1.0f - T) * logf(1.0f - Mc);
        }
    }
    acc = warpReduceSum(acc);
    __syncthreads();
    if (lane == 0) reds[w] = acc;
    __syncthreads();
    if (t == 0){
        float s = 0.f;
        for (int i = 0; i < 16; i++) s += reds[i];
        atomicAdd(out_l, s * (1.0f / (16.0f * 5.0f * 4096.0f)));
    }
}

// ---------------------------------------------------------------------------
// K6: per-batch epilogue: CAout = A@wv_w + wv_b; P2 = LN(P1+CAout);
// h = gelu(P2@w1+b1)@w2+b2; out = LN(P2+h). 16 blocks x 256 threads.
// ---------------------------------------------------------------------------
__global__ __launch_bounds__(256) void k_epilogue(
    const float* __restrict__ A, const float* __restrict__ P1,
    const float* __restrict__ wvw, const float* __restrict__ wvb,
    const float* __restrict__ clns, const float* __restrict__ clnb,
    const float* __restrict__ w1, const float* __restrict__ b1,
    const float* __restrict__ w2, const float* __restrict__ b2,
    const float* __restrict__ flns, const float* __restrict__ flnb,
    float* __restrict__ out)
{
    __shared__ float Al[1280], P2l[1280], hl[2560], s4[4];
    int b = blockIdx.x, t = threadIdx.x;
    for (int i = t; i < 1280; i += 256) Al[i] = A[(size_t)b*1280 + i];
    __syncthreads();
    float x[5];
    for (int n = 0; n < 5; n++){
        float a = wvb[t];
        for (int c = 0; c < 256; c++) a += Al[n*256 + c] * wvw[c*256 + t];
        x[n] = P1[n*256 + t] + a;
    }
    float p2[5];
    for (int n = 0; n < 5; n++){
        float sum  = blockSum256(x[n], s4);
        float mean = sum * (1.0f/256.0f);
        float d    = x[n] - mean;
        float sq   = blockSum256(d*d, s4);
        float rstd = rsqrtf(sq * (1.0f/256.0f) + 1e-5f);
        float y = d * rstd * clns[t] + clnb[t];
        p2[n] = y;
        P2l[n*256 + t] = y;
    }
    __syncthreads();
    for (int e = t; e < 512; e += 256){
        for (int n = 0; n < 5; n++){
            float a = b1[e];
            for (int c = 0; c < 256; c++) a += P2l[n*256 + c] * w1[c*512 + e];
            hl[n*512 + e] = 0.5f * a * (1.0f + erff(a * 0.70710678118654752f));
        }
    }
    __syncthreads();
    for (int n = 0; n < 5; n++){
        float a = b2[t];
        for (int e = 0; e < 512; e++) a += hl[n*512 + e] * w2[e*256 + t];
        x[n] = p2[n] + a;
    }
    for (int n = 0; n < 5; n++){
        float sum  = blockSum256(x[n], s4);
        float mean = sum * (1.0f/256.0f);
        float d    = x[n] - mean;
        float sq   = blockSum256(d*d, s4);
        float rstd = rsqrtf(sq * (1.0f/256.0f) + 1e-5f);
        out[((size_t)b*5 + n)*256 + t] = d * rstd * flns[t] + flnb[t];
    }
}

// ---------------------------------------------------------------------------
extern "C" void kernel_launch(void* const* d_in, const int* in_sizes, int n_in,
                              void* d_out, int out_size, void* d_ws, size_t ws_size,
                              hipStream_t stream)
{
    const float* Fd      = (const float*)d_in[0];
    const float* prompts = (const float*)d_in[1];
    const float* sa_q_w  = (const float*)d_in[2];
    const float* sa_q_b  = (const float*)d_in[3];
    const float* sa_k_w  = (const float*)d_in[4];
    const float* sa_k_b  = (const float*)d_in[5];
    const float* sa_v_w  = (const float*)d_in[6];
    const float* sa_v_b  = (const float*)d_in[7];
    const float* sa_ln_s = (const float*)d_in[8];
    const float* sa_ln_b = (const float*)d_in[9];
    const float* wq_w    = (const float*)d_in[10];
    const float* wq_b    = (const float*)d_in[11];
    const float* wk_w    = (const float*)d_in[12];
    const float* wk_b    = (const float*)d_in[13];
    const float* wv_w    = (const float*)d_in[14];
    const float* wv_b    = (const float*)d_in[15];
    const float* ca_ln_s = (const float*)d_in[16];
    const float* ca_ln_b = (const float*)d_in[17];
    const float* ffn_w1  = (const float*)d_in[18];
    const float* ffn_b1  = (const float*)d_in[19];
    const float* ffn_w2  = (const float*)d_in[20];
    const float* ffn_b2  = (const float*)d_in[21];
    const float* ffn_ln_s= (const float*)d_in[22];
    const float* ffn_ln_b= (const float*)d_in[23];

    float* out = (float*)d_out;
    float* ws  = (float*)d_ws;

    // workspace layout (floats)
    float* P1     = ws;                 // 1280
    float* Qk     = ws + 1280;          // 1280
    float* qkb    = ws + 2560;          // 5
    float* logits = ws + 4096;          // 16*5*4096 = 327680
    float* Mmat   = ws + 4096 + 327680; // 327680
    float* Amat   = ws + 4096 + 655360; // 16*5*256 = 20480

    // zero the L_ot accumulator (out[20480]); d_out is poisoned each run
    hipMemsetAsync(out + 20480, 0, sizeof(float), stream);

    k_prep<<<1, 256, 0, stream>>>(prompts, sa_q_w, sa_q_b, sa_k_w, sa_k_b,
                                  sa_v_w, sa_v_b, sa_ln_s, sa_ln_b,
                                  wq_w, wq_b, wk_w, wk_b, P1, Qk, qkb);
    k_logits<<<dim3(16, 16), 256, 0, stream>>>(Fd, Qk, qkb, logits);
    k_softmax<<<80, 256, 0, stream>>>(logits, Mmat);
    k_A<<<dim3(256, 16), 256, 0, stream>>>(Fd, Mmat, Amat);
    k_sinkhorn<<<16, 1024, 0, stream>>>(logits, Mmat, out + 20480);
    k_epilogue<<<16, 256, 0, stream>>>(Amat, P1, wv_w, wv_b, ca_ln_s, ca_ln_b,
                                       ffn_w1, ffn_b1, ffn_w2, ffn_b2,
                                       ffn_ln_s, ffn_ln_b, out);
}

// Round 4
// 450.915 us; speedup vs baseline: 1.0811x; 1.0811x over previous
//
#include <hip/hip_runtime.h>
#include <hip/hip_fp16.h>
#include <math.h>

__device__ __forceinline__ float warpReduceSum(float v){
#pragma unroll
    for (int off = 32; off > 0; off >>= 1) v += __shfl_down(v, off);
    return v;
}
__device__ __forceinline__ float warpReduceMax(float v){
#pragma unroll
    for (int off = 32; off > 0; off >>= 1) v = fmaxf(v, __shfl_down(v, off));
    return v;
}

// block of 256 threads (4 waves)
__device__ float blockSum256(float v, float* s4){
    v = warpReduceSum(v);
    int w = threadIdx.x >> 6;
    __syncthreads();
    if ((threadIdx.x & 63) == 0) s4[w] = v;
    __syncthreads();
    return s4[0] + s4[1] + s4[2] + s4[3];
}
// block of 512 threads (8 waves)
__device__ float blockSum512(float v, float* s8){
    v = warpReduceSum(v);
    int w = threadIdx.x >> 6;
    __syncthreads();
    if ((threadIdx.x & 63) == 0) s8[w] = v;
    __syncthreads();
    float s = 0.f;
#pragma unroll
    for (int i = 0; i < 8; i++) s += s8[i];
    return s;
}

// ---------------------------------------------------------------------------
// K0: weight folding. Wqk[d][c] = sum_e wq_w[d][e]*wk_w[c][e];
// bq2[c] = sum_e wq_b[e]*wk_w[c][e]; u[d] = sum_e wq_w[d][e]*wk_b[e].
// grid 256 blocks (d), 256 threads (c).
// ---------------------------------------------------------------------------
__global__ __launch_bounds__(256) void k_weight(
    const float* __restrict__ wqw, const float* __restrict__ wqb,
    const float* __restrict__ wkw, const float* __restrict__ wkb,
    float* __restrict__ Wqk, float* __restrict__ u, float* __restrict__ bq2)
{
    __shared__ float row[256], qbl[256], s4[4];
    int d = blockIdx.x, t = threadIdx.x;
    row[t] = wqw[d*256 + t];
    if (d == 0) qbl[t] = wqb[t];
    __syncthreads();
    const float* kr = wkw + t*256;
    float acc = 0.f;
#pragma unroll 8
    for (int e = 0; e < 256; e++) acc += row[e] * kr[e];
    Wqk[d*256 + t] = acc;
    if (d == 0){
        float acc2 = 0.f;
#pragma unroll 8
        for (int e = 0; e < 256; e++) acc2 += qbl[e] * kr[e];
        bq2[t] = acc2;
    }
    float pu = row[t] * wkb[t];
    pu = blockSum256(pu, s4);
    if (t == 0) u[d] = pu;
}

// ---------------------------------------------------------------------------
// K1: QKV projections of prompts. grid 12 blocks (3 mat x 4 col-chunks),
// 256 threads: col = chunk*64+(t&63), k-part p = t>>6 (64 c' each).
// ---------------------------------------------------------------------------
__global__ __launch_bounds__(256) void k_qkv(
    const float* __restrict__ prompts,
    const float* __restrict__ qw, const float* __restrict__ qb,
    const float* __restrict__ kw, const float* __restrict__ kb,
    const float* __restrict__ vw, const float* __restrict__ vb,
    float* __restrict__ QKV)
{
    __shared__ float Pl[1280];
    __shared__ float parts[4][5][64];
    int t = threadIdx.x;
    int mat = blockIdx.x >> 2, chunk = blockIdx.x & 3;
    for (int i = t; i < 1280; i += 256) Pl[i] = prompts[i];
    const float* W  = (mat == 0) ? qw : (mat == 1) ? kw : vw;
    const float* Bv = (mat == 0) ? qb : (mat == 1) ? kb : vb;
    int cl = t & 63, p = t >> 6;
    int col = chunk*64 + cl;
    __syncthreads();
    float acc[5] = {0,0,0,0,0};
    const float* wp = W + (size_t)(p*64)*256 + col;
#pragma unroll 4
    for (int c = 0; c < 64; c++){
        float wv = wp[(size_t)c*256];
#pragma unroll
        for (int n = 0; n < 5; n++) acc[n] += Pl[n*256 + p*64 + c] * wv;
    }
#pragma unroll
    for (int n = 0; n < 5; n++) parts[p][n][cl] = acc[n];
    __syncthreads();
    // 320 outputs with only 256 threads -> strided loop (the t<320 guard was
    // the round-2/3 bug: row n=4 was never written).
    for (int i = t; i < 320; i += 256){
        int n = i >> 6, c2 = i & 63;
        float s = parts[0][n][c2] + parts[1][n][c2] + parts[2][n][c2] + parts[3][n][c2]
                + Bv[chunk*64 + c2];
        QKV[mat*1280 + n*256 + chunk*64 + c2] = s;
    }
}

// ---------------------------------------------------------------------------
// K2: prompt self-attention epilogue (small) + P1 + qk = P1@Wqk+bq2 + qkb.
// 1 block x 256 threads.
// ---------------------------------------------------------------------------
__global__ __launch_bounds__(256) void k_attn(
    const float* __restrict__ QKV, const float* __restrict__ prompts,
    const float* __restrict__ lns, const float* __restrict__ lnb,
    const float* __restrict__ Wqk, const float* __restrict__ bq2,
    const float* __restrict__ u, const float* __restrict__ cwqb,
    const float* __restrict__ cwkb,
    float* __restrict__ P1g, float* __restrict__ qkg, float* __restrict__ qkbg)
{
    __shared__ float Pl[1280], Ql[1280], Kl[1280], Vl[1280], Sl[25], s4[4];
    int t = threadIdx.x;
    for (int i = t; i < 1280; i += 256){
        Pl[i] = prompts[i];
        Ql[i] = QKV[i];
        Kl[i] = QKV[1280 + i];
        Vl[i] = QKV[2560 + i];
    }
    __syncthreads();
    if (t < 25){
        int n = t / 5, m = t % 5;
        float s = 0.f;
        for (int c = 0; c < 256; c++) s += Ql[n*256 + c] * Kl[m*256 + c];
        Sl[t] = s * 0.0625f;
    }
    __syncthreads();
    if (t < 5){
        float mx = -1e30f;
        for (int m = 0; m < 5; m++) mx = fmaxf(mx, Sl[t*5 + m]);
        float e[5], sm = 0.f;
        for (int m = 0; m < 5; m++){ e[m] = expf(Sl[t*5 + m] - mx); sm += e[m]; }
        for (int m = 0; m < 5; m++) Sl[t*5 + m] = e[m] / sm;
    }
    __syncthreads();
    float x[5];
#pragma unroll
    for (int n = 0; n < 5; n++){
        float s = 0.f;
        for (int m = 0; m < 5; m++) s += Sl[n*5 + m] * Vl[m*256 + t];
        x[n] = Pl[n*256 + t] + s;
    }
#pragma unroll
    for (int n = 0; n < 5; n++){
        float sum  = blockSum256(x[n], s4);
        float mean = sum * (1.0f/256.0f);
        float d    = x[n] - mean;
        float sq   = blockSum256(d*d, s4);
        float rstd = rsqrtf(sq * (1.0f/256.0f) + 1e-5f);
        float y = d * rstd * lns[t] + lnb[t];
        Pl[n*256 + t] = y;
        P1g[n*256 + t] = y;
    }
    __syncthreads();
    // qk[n][t] = sum_d P1[n][d]*Wqk[d][t] + bq2[t]
    float qa[5] = {0,0,0,0,0};
    const float* wp = Wqk + t;
#pragma unroll 4
    for (int d = 0; d < 256; d++){
        float wv = wp[(size_t)d*256];
#pragma unroll
        for (int n = 0; n < 5; n++) qa[n] += Pl[n*256 + d] * wv;
    }
    float bb = bq2[t];
#pragma unroll
    for (int n = 0; n < 5; n++) qkg[n*256 + t] = qa[n] + bb;
    // qkb[n] = P1[n].u + wq_b.wk_b
    float s0 = blockSum256(cwqb[t] * cwkb[t], s4);
#pragma unroll
    for (int n = 0; n < 5; n++){
        float qn = blockSum256(Pl[n*256 + t] * u[t], s4);
        if (t == 0) qkbg[n] = qn + s0;
    }
}

// ---------------------------------------------------------------------------
// K3: logits[b,n,m] = scale*(qk[n,:].Fd[b,:,m] + qkb[n]). grid (16,16) x 256.
// ---------------------------------------------------------------------------
__global__ __launch_bounds__(256) void k_logits(
    const float* __restrict__ Fd, const float* __restrict__ qkg,
    const float* __restrict__ qkbg, float* __restrict__ logits)
{
    __shared__ float qk[1280];
    __shared__ float qb5[5];
    int t = threadIdx.x;
    for (int i = t; i < 1280; i += 256) qk[i] = qkg[i];
    if (t < 5) qb5[t] = qkbg[t];
    __syncthreads();
    int b = blockIdx.y;
    int m = blockIdx.x * 256 + t;
    const float* fp = Fd + ((size_t)b * 256) * 4096 + m;
    float a0 = qb5[0], a1 = qb5[1], a2 = qb5[2], a3 = qb5[3], a4 = qb5[4];
#pragma unroll 4
    for (int c = 0; c < 256; c++){
        float f = fp[(size_t)c * 4096];
        a0 += qk[c]        * f;
        a1 += qk[256 + c]  * f;
        a2 += qk[512 + c]  * f;
        a3 += qk[768 + c]  * f;
        a4 += qk[1024 + c] * f;
    }
    float* lp = logits + ((size_t)b * 5) * 4096 + m;
    lp[0]     = a0 * 0.0625f;
    lp[4096]  = a1 * 0.0625f;
    lp[8192]  = a2 * 0.0625f;
    lp[12288] = a3 * 0.0625f;
    lp[16384] = a4 * 0.0625f;
}

// ---------------------------------------------------------------------------
// K4: A[b,n,c] = sum_m softmax(logits[b,n,:])[m] * Fd[b,c,m]
// grid (cc=16, b=16) x 1024 threads. Softmax stats computed in-block;
// M staged in LDS as __half (40KB — static LDS must stay <= 64KB).
// wave w owns c = cc*16+w.
// ---------------------------------------------------------------------------
__global__ __launch_bounds__(1024) void k_A(
    const float* __restrict__ Fd, const float* __restrict__ logits,
    float* __restrict__ A)
{
    __shared__ __align__(16) __half Ml[5*4096];
    __shared__ float red[80];
    int b = blockIdx.y, cc = blockIdx.x, t = threadIdx.x;
    int w = t >> 6, lane = t & 63;
    const float* Lb = logits + (size_t)(b*5) * 4096;
    float ll[5][4];
#pragma unroll
    for (int n = 0; n < 5; n++)
#pragma unroll
        for (int k = 0; k < 4; k++)
            ll[n][k] = Lb[n*4096 + t + k*1024];
    // block max per row
#pragma unroll
    for (int n = 0; n < 5; n++){
        float tm = fmaxf(fmaxf(ll[n][0], ll[n][1]), fmaxf(ll[n][2], ll[n][3]));
        tm = warpReduceMax(tm);
        if (lane == 0) red[w*5 + n] = tm;
    }
    __syncthreads();
    float mx[5];
#pragma unroll
    for (int n = 0; n < 5; n++){
        float gm = -1e30f;
        for (int i = 0; i < 16; i++) gm = fmaxf(gm, red[i*5 + n]);
        mx[n] = gm;
    }
    __syncthreads();
    float e[5][4];
#pragma unroll
    for (int n = 0; n < 5; n++){
        float ps = 0.f;
#pragma unroll
        for (int k = 0; k < 4; k++){ e[n][k] = expf(ll[n][k] - mx[n]); ps += e[n][k]; }
        ps = warpReduceSum(ps);
        if (lane == 0) red[w*5 + n] = ps;
    }
    __syncthreads();
#pragma unroll
    for (int n = 0; n < 5; n++){
        float z = 0.f;
        for (int i = 0; i < 16; i++) z += red[i*5 + n];
        float inv = 1.0f / z;
#pragma unroll
        for (int k = 0; k < 4; k++)
            Ml[n*4096 + t + k*1024] = __float2half(e[n][k] * inv);
    }
    __syncthreads();
    // wave-owned column c
    int c = cc*16 + w;
    const float* fp = Fd + ((size_t)(b*256 + c)) * 4096;
    float4 a4[5];
#pragma unroll
    for (int n = 0; n < 5; n++) a4[n] = make_float4(0.f, 0.f, 0.f, 0.f);
    for (int it = 0; it < 16; it++){
        int m4 = it*256 + (lane << 2);
        float4 f = *(const float4*)(fp + m4);
#pragma unroll
        for (int n = 0; n < 5; n++){
            const __half2* mp = (const __half2*)(Ml + n*4096 + m4);
            float2 m0 = __half22float2(mp[0]);
            float2 m1 = __half22float2(mp[1]);
            a4[n].x += m0.x * f.x; a4[n].y += m0.y * f.y;
            a4[n].z += m1.x * f.z; a4[n].w += m1.y * f.w;
        }
    }
#pragma unroll
    for (int n = 0; n < 5; n++){
        float s = a4[n].x + a4[n].y + a4[n].z + a4[n].w;
        s = warpReduceSum(s);
        if (lane == 0) A[(size_t)(b*5 + n)*256 + c] = s;
    }
}

// ---------------------------------------------------------------------------
// K5: per-batch Sinkhorn + BCE (M recomputed in-kernel). 16 blocks x 1024.
// ---------------------------------------------------------------------------
__global__ __launch_bounds__(1024) void k_sinkhorn(
    const float* __restrict__ logits, float* __restrict__ out_l)
{
    __shared__ float lv[4096];
    __shared__ float redm[80], reds[80];
    __shared__ float nl[5];
    int b = blockIdx.x, t = threadIdx.x;
    int w = t >> 6, lane = t & 63;
    const float* Lb = logits + (size_t)b * 5 * 4096;
    float lk[5][4];
#pragma unroll
    for (int n = 0; n < 5; n++)
#pragma unroll
        for (int k = 0; k < 4; k++)
            lk[n][k] = Lb[n*4096 + t + k*1024] / 0.05f;
#pragma unroll
    for (int k = 0; k < 4; k++) lv[t + k*1024] = 0.0f;
    float lu[5] = {0,0,0,0,0};
    const float log_mu = logf(0.2f + 1e-8f);
    const float log_nu = logf((1.0f/4096.0f) + 1e-8f);
    __syncthreads();

    float diff = 1e30f;
    for (int it = 0; it < 100; ++it){
        if (diff < 1e-4f) break;
        float lvk[4];
#pragma unroll
        for (int k = 0; k < 4; k++) lvk[k] = lv[t + k*1024];
#pragma unroll
        for (int n = 0; n < 5; n++){
            float v0 = lk[n][0] + lvk[0], v1 = lk[n][1] + lvk[1];
            float v2 = lk[n][2] + lvk[2], v3 = lk[n][3] + lvk[3];
            float lm = fmaxf(fmaxf(v0, v1), fmaxf(v2, v3));
            float ps = expf(v0-lm) + expf(v1-lm) + expf(v2-lm) + expf(v3-lm);
            float wm = lm;
#pragma unroll
            for (int off = 1; off < 64; off <<= 1) wm = fmaxf(wm, __shfl_xor(wm, off));
            float contrib = ps * expf(lm - wm);
#pragma unroll
            for (int off = 1; off < 64; off <<= 1) contrib += __shfl_xor(contrib, off);
            if (lane == 0){ redm[w*5 + n] = wm; reds[w*5 + n] = contrib; }
        }
        __syncthreads();
        if (t < 5){
            float gm = -1e30f;
            for (int i = 0; i < 16; i++) gm = fmaxf(gm, redm[i*5 + t]);
            float gs = 0.f;
            for (int i = 0; i < 16; i++) gs += reds[i*5 + t] * expf(redm[i*5 + t] - gm);
            nl[t] = log_mu - (gm + logf(gs));
        }
        __syncthreads();
        float nlr[5], nd = 0.f;
#pragma unroll
        for (int n = 0; n < 5; n++){
            nlr[n] = nl[n];
            nd = fmaxf(nd, fabsf(nlr[n] - lu[n]));
            lu[n] = nlr[n];
        }
        diff = nd;
#pragma unroll
        for (int k = 0; k < 4; k++){
            float x0 = lk[0][k] + nlr[0], x1 = lk[1][k] + nlr[1];
            float x2 = lk[2][k] + nlr[2], x3 = lk[3][k] + nlr[3];
            float x4 = lk[4][k] + nlr[4];
            float cm = fmaxf(fmaxf(fmaxf(x0, x1), fmaxf(x2, x3)), x4);
            float cs = expf(x0-cm) + expf(x1-cm) + expf(x2-cm) + expf(x3-cm) + expf(x4-cm);
            lv[t + k*1024] = log_nu - (cm + logf(cs));
        }
        __syncthreads();
    }
    // --- softmax row stats of logits (for M) ---
    float mx5[5], iz5[5];
#pragma unroll
    for (int n = 0; n < 5; n++){
        float l0 = lk[n][0]*0.05f, l1 = lk[n][1]*0.05f;
        float l2 = lk[n][2]*0.05f, l3 = lk[n][3]*0.05f;
        float tm = fmaxf(fmaxf(l0, l1), fmaxf(l2, l3));
        tm = warpReduceMax(tm);
        if (lane == 0) redm[w*5 + n] = tm;
    }
    __syncthreads();
#pragma unroll
    for (int n = 0; n < 5; n++){
        float gm = -1e30f;
        for (int i = 0; i < 16; i++) gm = fmaxf(gm, redm[i*5 + n]);
        mx5[n] = gm;
    }
    __syncthreads();
#pragma unroll
    for (int n = 0; n < 5; n++){
        float ps = 0.f;
#pragma unroll
        for (int k = 0; k < 4; k++) ps += expf(lk[n][k]*0.05f - mx5[n]);
        ps = warpReduceSum(ps);
        if (lane == 0) redm[w*5 + n] = ps;
    }
    __syncthreads();
#pragma unroll
    for (int n = 0; n < 5; n++){
        float z = 0.f;
        for (int i = 0; i < 16; i++) z += redm[i*5 + n];
        iz5[n] = 1.0f / z;
    }
    // --- BCE(T, M) ---
    float acc = 0.f;
#pragma unroll
    for (int n = 0; n < 5; n++){
#pragma unroll
        for (int k = 0; k < 4; k++){
            int m = t + k*1024;
            float Mv = expf(lk[n][k]*0.05f - mx5[n]) * iz5[n];
            float Mc = fminf(fmaxf(Mv, 1e-6f), 1.0f - 1e-6f);
            float lT = lu[n] + lk[n][k] + lv[m];
            float T  = fminf(expf(lT), 1.0f);
            acc -= T * logf(Mc) + (1.0f - T) * logf(1.0f - Mc);
        }
    }
    acc = warpReduceSum(acc);
    __syncthreads();
    if (lane == 0) reds[w] = acc;
    __syncthreads();
    if (t == 0){
        float s = 0.f;
        for (int i = 0; i < 16; i++) s += reds[i];
        atomicAdd(out_l, s * (1.0f / (16.0f * 5.0f * 4096.0f)));
    }
}

// ---------------------------------------------------------------------------
// K6: epilogue, one block per (b,n) row. 80 blocks x 512 threads.
// ---------------------------------------------------------------------------
__global__ __launch_bounds__(512) void k_epilogue(
    const float* __restrict__ A, const float* __restrict__ P1,
    const float* __restrict__ wvw, const float* __restrict__ wvb,
    const float* __restrict__ clns, const float* __restrict__ clnb,
    const float* __restrict__ w1, const float* __restrict__ b1,
    const float* __restrict__ w2, const float* __restrict__ b2,
    const float* __restrict__ flns, const float* __restrict__ flnb,
    float* __restrict__ out)
{
    __shared__ float Ar[256], P1r[256], P2[256], hl[512], parts[2][256], s8[8];
    int bn = blockIdx.x;
    int n = bn % 5;
    int t = threadIdx.x;
    if (t < 256){ Ar[t] = A[(size_t)bn*256 + t]; P1r[t] = P1[n*256 + t]; }
    __syncthreads();
    int c = t & 255, p = t >> 8;
    {
        float acc = 0.f;
        const float* wp = wvw + (size_t)(p*128)*256 + c;
#pragma unroll 4
        for (int k = 0; k < 128; k++) acc += Ar[p*128 + k] * wp[(size_t)k*256];
        parts[p][c] = acc;
    }
    __syncthreads();
    float x = 0.f;
    if (t < 256) x = P1r[t] + parts[0][t] + parts[1][t] + wvb[t];
    // LN #1
    float sum  = blockSum512((t < 256) ? x : 0.f, s8);
    float mean = sum * (1.0f/256.0f);
    float d    = x - mean;
    float sq   = blockSum512((t < 256) ? d*d : 0.f, s8);
    float rstd = rsqrtf(sq * (1.0f/256.0f) + 1e-5f);
    float p2v = 0.f;
    if (t < 256){
        p2v = d * rstd * clns[t] + clnb[t];
        P2[t] = p2v;
    }
    __syncthreads();
    // FFN1: e = t
    {
        float a = b1[t];
        const float* wp = w1 + t;
#pragma unroll 4
        for (int k = 0; k < 256; k++) a += P2[k] * wp[(size_t)k*512];
        hl[t] = 0.5f * a * (1.0f + erff(a * 0.70710678118654752f));
    }
    __syncthreads();
    // FFN2
    {
        float acc = 0.f;
        const float* wp = w2 + (size_t)(p*256)*256 + c;
#pragma unroll 4
        for (int k = 0; k < 256; k++) acc += hl[p*256 + k] * wp[(size_t)k*256];
        parts[p][c] = acc;
    }
    __syncthreads();
    float x2 = 0.f;
    if (t < 256) x2 = P2[t] + parts[0][t] + parts[1][t] + b2[t];
    // LN #2
    float sum2  = blockSum512((t < 256) ? x2 : 0.f, s8);
    float mean2 = sum2 * (1.0f/256.0f);
    float d2    = x2 - mean2;
    float sq2   = blockSum512((t < 256) ? d2*d2 : 0.f, s8);
    float rstd2 = rsqrtf(sq2 * (1.0f/256.0f) + 1e-5f);
    if (t < 256) out[(size_t)bn*256 + t] = d2 * rstd2 * flns[t] + flnb[t];
}

// ---------------------------------------------------------------------------
extern "C" void kernel_launch(void* const* d_in, const int* in_sizes, int n_in,
                              void* d_out, int out_size, void* d_ws, size_t ws_size,
                              hipStream_t stream)
{
    const float* Fd      = (const float*)d_in[0];
    const float* prompts = (const float*)d_in[1];
    const float* sa_q_w  = (const float*)d_in[2];
    const float* sa_q_b  = (const float*)d_in[3];
    const float* sa_k_w  = (const float*)d_in[4];
    const float* sa_k_b  = (const float*)d_in[5];
    const float* sa_v_w  = (const float*)d_in[6];
    const float* sa_v_b  = (const float*)d_in[7];
    const float* sa_ln_s = (const float*)d_in[8];
    const float* sa_ln_b = (const float*)d_in[9];
    const float* wq_w    = (const float*)d_in[10];
    const float* wq_b    = (const float*)d_in[11];
    const float* wk_w    = (const float*)d_in[12];
    const float* wk_b    = (const float*)d_in[13];
    const float* wv_w    = (const float*)d_in[14];
    const float* wv_b    = (const float*)d_in[15];
    const float* ca_ln_s = (const float*)d_in[16];
    const float* ca_ln_b = (const float*)d_in[17];
    const float* ffn_w1  = (const float*)d_in[18];
    const float* ffn_b1  = (const float*)d_in[19];
    const float* ffn_w2  = (const float*)d_in[20];
    const float* ffn_b2  = (const float*)d_in[21];
    const float* ffn_ln_s= (const float*)d_in[22];
    const float* ffn_ln_b= (const float*)d_in[23];

    float* out = (float*)d_out;
    float* ws  = (float*)d_ws;

    // workspace layout (floats)
    float* P1     = ws;            // 1280
    float* qkb    = ws + 1536;     // 5
    float* QKV    = ws + 2048;     // 3840
    float* u      = ws + 6144;     // 256
    float* bq2    = ws + 6400;     // 256
    float* qkg    = ws + 6656;     // 1280
    float* Wqk    = ws + 8192;     // 65536
    float* logits = ws + 73728;    // 327680
    float* Amat   = ws + 401408;   // 20480

    hipMemsetAsync(out + 20480, 0, sizeof(float), stream);

    k_weight<<<256, 256, 0, stream>>>(wq_w, wq_b, wk_w, wk_b, Wqk, u, bq2);
    k_qkv<<<12, 256, 0, stream>>>(prompts, sa_q_w, sa_q_b, sa_k_w, sa_k_b,
                                  sa_v_w, sa_v_b, QKV);
    k_attn<<<1, 256, 0, stream>>>(QKV, prompts, sa_ln_s, sa_ln_b, Wqk, bq2,
                                  u, wq_b, wk_b, P1, qkg, qkb);
    k_logits<<<dim3(16, 16), 256, 0, stream>>>(Fd, qkg, qkb, logits);
    k_A<<<dim3(16, 16), 1024, 0, stream>>>(Fd, logits, Amat);
    k_sinkhorn<<<16, 1024, 0, stream>>>(logits, out + 20480);
    k_epilogue<<<80, 512, 0, stream>>>(Amat, P1, wv_w, wv_b, ca_ln_s, ca_ln_b,
                                       ffn_w1, ffn_b1, ffn_w2, ffn_b2,
                                       ffn_ln_s, ffn_ln_b, out);
}

// Round 5
// 323.268 us; speedup vs baseline: 1.5080x; 1.3949x over previous
//
#include <hip/hip_runtime.h>
#include <hip/hip_fp16.h>
#include <math.h>

#define LOG2E 1.44269504088896340f
#define LN2   0.69314718055994531f

__device__ __forceinline__ float warpReduceSum(float v){
#pragma unroll
    for (int off = 32; off > 0; off >>= 1) v += __shfl_down(v, off);
    return v;
}
__device__ __forceinline__ float warpReduceMax(float v){
#pragma unroll
    for (int off = 32; off > 0; off >>= 1) v = fmaxf(v, __shfl_down(v, off));
    return v;
}

// block of 256 threads (4 waves)
__device__ float blockSum256(float v, float* s4){
    v = warpReduceSum(v);
    int w = threadIdx.x >> 6;
    __syncthreads();
    if ((threadIdx.x & 63) == 0) s4[w] = v;
    __syncthreads();
    return s4[0] + s4[1] + s4[2] + s4[3];
}
// block of 512 threads (8 waves)
__device__ float blockSum512(float v, float* s8){
    v = warpReduceSum(v);
    int w = threadIdx.x >> 6;
    __syncthreads();
    if ((threadIdx.x & 63) == 0) s8[w] = v;
    __syncthreads();
    float s = 0.f;
#pragma unroll
    for (int i = 0; i < 8; i++) s += s8[i];
    return s;
}

// ---------------------------------------------------------------------------
// K0: weight folding. Wqk[d][c] = sum_e wq_w[d][e]*wk_w[c][e];
// bq2[c] = sum_e wq_b[e]*wk_w[c][e]; u[d] = sum_e wq_w[d][e]*wk_b[e].
// grid 256 blocks (d), 256 threads (c). wkw staged through LDS tiles so the
// global reads are coalesced (per-thread row reads were 1KB-strided).
// ---------------------------------------------------------------------------
__global__ __launch_bounds__(256) void k_weight(
    const float* __restrict__ wqw, const float* __restrict__ wqb,
    const float* __restrict__ wkw, const float* __restrict__ wkb,
    float* __restrict__ Wqk, float* __restrict__ u, float* __restrict__ bq2)
{
    __shared__ float row[256], qbl[256], s4[4];
    __shared__ float tile[256][33];   // [c][e-tile of 32], pad to 33 (bank)
    int d = blockIdx.x, t = threadIdx.x;
    row[t] = wqw[d*256 + t];
    qbl[t] = wqb[t];
    float acc = 0.f, acc2 = 0.f;
    for (int e0 = 0; e0 < 256; e0 += 32){
        __syncthreads();
        // 8192 elements, 32 per thread, coalesced 128B runs
#pragma unroll
        for (int j = 0; j < 32; j++){
            int idx = t + j*256;
            int c = idx >> 5, e = idx & 31;
            tile[c][e] = wkw[c*256 + e0 + e];
        }
        __syncthreads();
#pragma unroll
        for (int e = 0; e < 32; e++){
            float tv = tile[t][e];
            acc  += row[e0+e] * tv;
            acc2 += qbl[e0+e] * tv;
        }
    }
    Wqk[d*256 + t] = acc;
    if (d == 0) bq2[t] = acc2;
    float pu = blockSum256(row[t] * wkb[t], s4);
    if (t == 0) u[d] = pu;
}

// ---------------------------------------------------------------------------
// K1: QKV projections of prompts. grid 12 blocks (3 mat x 4 col-chunks).
// ---------------------------------------------------------------------------
__global__ __launch_bounds__(256) void k_qkv(
    const float* __restrict__ prompts,
    const float* __restrict__ qw, const float* __restrict__ qb,
    const float* __restrict__ kw, const float* __restrict__ kb,
    const float* __restrict__ vw, const float* __restrict__ vb,
    float* __restrict__ QKV)
{
    __shared__ float Pl[1280];
    __shared__ float parts[4][5][64];
    int t = threadIdx.x;
    int mat = blockIdx.x >> 2, chunk = blockIdx.x & 3;
    for (int i = t; i < 1280; i += 256) Pl[i] = prompts[i];
    const float* W  = (mat == 0) ? qw : (mat == 1) ? kw : vw;
    const float* Bv = (mat == 0) ? qb : (mat == 1) ? kb : vb;
    int cl = t & 63, p = t >> 6;
    int col = chunk*64 + cl;
    __syncthreads();
    float acc[5] = {0,0,0,0,0};
    const float* wp = W + (size_t)(p*64)*256 + col;
#pragma unroll 8
    for (int c = 0; c < 64; c++){
        float wv = wp[(size_t)c*256];
#pragma unroll
        for (int n = 0; n < 5; n++) acc[n] += Pl[n*256 + p*64 + c] * wv;
    }
#pragma unroll
    for (int n = 0; n < 5; n++) parts[p][n][cl] = acc[n];
    __syncthreads();
    // 320 outputs, 256 threads -> strided
    for (int i = t; i < 320; i += 256){
        int n = i >> 6, c2 = i & 63;
        float s = parts[0][n][c2] + parts[1][n][c2] + parts[2][n][c2] + parts[3][n][c2]
                + Bv[chunk*64 + c2];
        QKV[mat*1280 + n*256 + chunk*64 + c2] = s;
    }
}

// ---------------------------------------------------------------------------
// K2: prompt self-attention + LN -> P1. 1 block x 256 threads (small only).
// ---------------------------------------------------------------------------
__global__ __launch_bounds__(256) void k_attn(
    const float* __restrict__ QKV, const float* __restrict__ prompts,
    const float* __restrict__ lns, const float* __restrict__ lnb,
    float* __restrict__ P1g)
{
    __shared__ float Pl[1280], Ql[1280], Kl[1280], Vl[1280], Sl[25], s4[4];
    int t = threadIdx.x;
    for (int i = t; i < 1280; i += 256){
        Pl[i] = prompts[i];
        Ql[i] = QKV[i];
        Kl[i] = QKV[1280 + i];
        Vl[i] = QKV[2560 + i];
    }
    __syncthreads();
    if (t < 25){
        int n = t / 5, m = t % 5;
        float s = 0.f;
        for (int c = 0; c < 256; c++) s += Ql[n*256 + c] * Kl[m*256 + c];
        Sl[t] = s * 0.0625f;
    }
    __syncthreads();
    if (t < 5){
        float mx = -1e30f;
        for (int m = 0; m < 5; m++) mx = fmaxf(mx, Sl[t*5 + m]);
        float e[5], sm = 0.f;
        for (int m = 0; m < 5; m++){ e[m] = expf(Sl[t*5 + m] - mx); sm += e[m]; }
        for (int m = 0; m < 5; m++) Sl[t*5 + m] = e[m] / sm;
    }
    __syncthreads();
    float x[5];
#pragma unroll
    for (int n = 0; n < 5; n++){
        float s = 0.f;
        for (int m = 0; m < 5; m++) s += Sl[n*5 + m] * Vl[m*256 + t];
        x[n] = Pl[n*256 + t] + s;
    }
#pragma unroll
    for (int n = 0; n < 5; n++){
        float sum  = blockSum256(x[n], s4);
        float mean = sum * (1.0f/256.0f);
        float d    = x[n] - mean;
        float sq   = blockSum256(d*d, s4);
        float rstd = rsqrtf(sq * (1.0f/256.0f) + 1e-5f);
        P1g[n*256 + t] = d * rstd * lns[t] + lnb[t];
    }
}

// ---------------------------------------------------------------------------
// K2b: qk[n][c] = sum_d P1[n][d]*Wqk[d][c] + bq2[c];
//      qkb[n]  = sum_d P1[n][d]*u[d] + wq_b.wk_b.  5 blocks (n) x 256 thr.
// ---------------------------------------------------------------------------
__global__ __launch_bounds__(256) void k_qk(
    const float* __restrict__ P1, const float* __restrict__ Wqk,
    const float* __restrict__ bq2, const float* __restrict__ u,
    const float* __restrict__ cwqb, const float* __restrict__ cwkb,
    float* __restrict__ qkg, float* __restrict__ qkbg)
{
    __shared__ float Pr[256], s4[4];
    int n = blockIdx.x, t = threadIdx.x;
    Pr[t] = P1[n*256 + t];
    __syncthreads();
    float acc = 0.f;
    const float* wp = Wqk + t;
#pragma unroll 16
    for (int d = 0; d < 256; d++) acc += Pr[d] * wp[(size_t)d*256];
    qkg[n*256 + t] = acc + bq2[t];
    float pu = blockSum256(Pr[t]*u[t] + cwqb[t]*cwkb[t], s4);
    if (t == 0) qkbg[n] = pu;
}

// ---------------------------------------------------------------------------
// K3: logits[b,n,m] = scale*(qk[n,:].Fd[b,:,m] + qkb[n]). grid (16,16) x 256.
// unroll 16 for memory-level parallelism (latency-bound otherwise).
// ---------------------------------------------------------------------------
__global__ __launch_bounds__(256) void k_logits(
    const float* __restrict__ Fd, const float* __restrict__ qkg,
    const float* __restrict__ qkbg, float* __restrict__ logits)
{
    __shared__ float qk[1280];
    __shared__ float qb5[5];
    int t = threadIdx.x;
    for (int i = t; i < 1280; i += 256) qk[i] = qkg[i];
    if (t < 5) qb5[t] = qkbg[t];
    __syncthreads();
    int b = blockIdx.y;
    int m = blockIdx.x * 256 + t;
    const float* fp = Fd + ((size_t)b * 256) * 4096 + m;
    float a0 = qb5[0], a1 = qb5[1], a2 = qb5[2], a3 = qb5[3], a4 = qb5[4];
#pragma unroll 16
    for (int c = 0; c < 256; c++){
        float f = fp[(size_t)c * 4096];
        a0 += qk[c]        * f;
        a1 += qk[256 + c]  * f;
        a2 += qk[512 + c]  * f;
        a3 += qk[768 + c]  * f;
        a4 += qk[1024 + c] * f;
    }
    float* lp = logits + ((size_t)b * 5) * 4096 + m;
    lp[0]     = a0 * 0.0625f;
    lp[4096]  = a1 * 0.0625f;
    lp[8192]  = a2 * 0.0625f;
    lp[12288] = a3 * 0.0625f;
    lp[16384] = a4 * 0.0625f;
}

// ---------------------------------------------------------------------------
// K4: A[b,n,c] = sum_m softmax(logits[b,n,:])[m] * Fd[b,c,m]
// grid (cc=16, b=16) x 1024. M staged in LDS as __half (40KB).
// ---------------------------------------------------------------------------
__global__ __launch_bounds__(1024) void k_A(
    const float* __restrict__ Fd, const float* __restrict__ logits,
    float* __restrict__ A)
{
    __shared__ __align__(16) __half Ml[5*4096];
    __shared__ float red[80];
    int b = blockIdx.y, cc = blockIdx.x, t = threadIdx.x;
    int w = t >> 6, lane = t & 63;
    const float* Lb = logits + (size_t)(b*5) * 4096;
    float ll[5][4];
#pragma unroll
    for (int n = 0; n < 5; n++)
#pragma unroll
        for (int k = 0; k < 4; k++)
            ll[n][k] = Lb[n*4096 + t + k*1024];
#pragma unroll
    for (int n = 0; n < 5; n++){
        float tm = fmaxf(fmaxf(ll[n][0], ll[n][1]), fmaxf(ll[n][2], ll[n][3]));
        tm = warpReduceMax(tm);
        if (lane == 0) red[w*5 + n] = tm;
    }
    __syncthreads();
    float mx[5];
#pragma unroll
    for (int n = 0; n < 5; n++){
        float gm = -1e30f;
        for (int i = 0; i < 16; i++) gm = fmaxf(gm, red[i*5 + n]);
        mx[n] = gm;
    }
    __syncthreads();
    float e[5][4];
#pragma unroll
    for (int n = 0; n < 5; n++){
        float ps = 0.f;
#pragma unroll
        for (int k = 0; k < 4; k++){ e[n][k] = expf(ll[n][k] - mx[n]); ps += e[n][k]; }
        ps = warpReduceSum(ps);
        if (lane == 0) red[w*5 + n] = ps;
    }
    __syncthreads();
#pragma unroll
    for (int n = 0; n < 5; n++){
        float z = 0.f;
        for (int i = 0; i < 16; i++) z += red[i*5 + n];
        float inv = 1.0f / z;
#pragma unroll
        for (int k = 0; k < 4; k++)
            Ml[n*4096 + t + k*1024] = __float2half(e[n][k] * inv);
    }
    __syncthreads();
    int c = cc*16 + w;
    const float* fp = Fd + ((size_t)(b*256 + c)) * 4096;
    float4 a4[5];
#pragma unroll
    for (int n = 0; n < 5; n++) a4[n] = make_float4(0.f, 0.f, 0.f, 0.f);
#pragma unroll 4
    for (int it = 0; it < 16; it++){
        int m4 = it*256 + (lane << 2);
        float4 f = *(const float4*)(fp + m4);
#pragma unroll
        for (int n = 0; n < 5; n++){
            const __half2* mp = (const __half2*)(Ml + n*4096 + m4);
            float2 m0 = __half22float2(mp[0]);
            float2 m1 = __half22float2(mp[1]);
            a4[n].x += m0.x * f.x; a4[n].y += m0.y * f.y;
            a4[n].z += m1.x * f.z; a4[n].w += m1.y * f.w;
        }
    }
#pragma unroll
    for (int n = 0; n < 5; n++){
        float s = a4[n].x + a4[n].y + a4[n].z + a4[n].w;
        s = warpReduceSum(s);
        if (lane == 0) A[(size_t)(b*5 + n)*256 + c] = s;
    }
}

// ---------------------------------------------------------------------------
// K5: per-batch Sinkhorn + BCE, LINEAR domain. 16 blocks x 1024 threads.
// Each thread owns columns m = t + k*1024 (k=0..3) for all 5 rows.
// ek = 2^(log_K*log2e) precomputed; iteration is FMA-only:
//   gs_n = sum_m ek*vv  -> en = mu/gs ;  cs_k = sum_n ek*en -> vv = nu/cs.
// Convergence diff tracked via lu2 (log2 domain), 5 log2f/iter.
// One barrier per iteration (parity double-buffered wave partials).
// Dynamic range is tiny here (|log2 K| <~ 15), so no max-subtraction needed.
// ---------------------------------------------------------------------------
__global__ __launch_bounds__(1024) void k_sinkhorn(
    const float* __restrict__ logits, float* __restrict__ out_l)
{
    __shared__ float redm[2][16][5], reds[16][5];
    __shared__ float redb[16];
    int b = blockIdx.x, t = threadIdx.x;
    int w = t >> 6, lane = t & 63;
    const float* Lb = logits + (size_t)b * 5 * 4096;
    float lk2[5][4], ek[5][4];
#pragma unroll
    for (int n = 0; n < 5; n++)
#pragma unroll
        for (int k = 0; k < 4; k++){
            float lv = (Lb[n*4096 + t + k*1024] / 0.05f) * LOG2E;  // log2 K
            lk2[n][k] = lv;
            ek[n][k] = exp2f(lv);
        }
    const float mu_lin  = 0.2f + 1e-8f;
    const float nu_lin  = 1.0f/4096.0f + 1e-8f;
    const float log2mu  = log2f(mu_lin);
    const float log2nu  = log2f(nu_lin);
    const float TOL2    = 1e-4f * LOG2E;   // TOL in log2 units

    float vv[4]  = {1.f, 1.f, 1.f, 1.f};   // linear v (lv=0)
    float lu2[5] = {0,0,0,0,0};
    float lv2[4] = {0,0,0,0};
    float en[5];
    float diff = 1e30f;
    int par = 0;

    for (int it = 0; it < 100; ++it){
        if (diff < TOL2) break;
        // row partial sums over this thread's 4 columns
        float gs[5];
#pragma unroll
        for (int n = 0; n < 5; n++)
            gs[n] = ek[n][0]*vv[0] + ek[n][1]*vv[1] + ek[n][2]*vv[2] + ek[n][3]*vv[3];
        // wave sum-reduce (butterfly -> lane-uniform)
#pragma unroll
        for (int off = 1; off < 64; off <<= 1){
#pragma unroll
            for (int n = 0; n < 5; n++) gs[n] += __shfl_xor(gs[n], off);
        }
        if (lane == 0){
#pragma unroll
            for (int n = 0; n < 5; n++) redm[par][w][n] = gs[n];
        }
        __syncthreads();
        // redundant combine of 16 wave partials (cheap: adds only)
        float nd = 0.f;
#pragma unroll
        for (int n = 0; n < 5; n++){
            float s = 0.f;
            for (int i = 0; i < 16; i++) s += redm[par][i][n];
            float nl = log2mu - log2f(s);
            nd = fmaxf(nd, fabsf(nl - lu2[n]));
            lu2[n] = nl;
            en[n] = mu_lin / s;
        }
        diff = nd;
        // column update (thread-local, no reduction)
#pragma unroll
        for (int k = 0; k < 4; k++){
            float cs = ek[0][k]*en[0] + ek[1][k]*en[1] + ek[2][k]*en[2]
                     + ek[3][k]*en[3] + ek[4][k]*en[4];
            vv[k]  = nu_lin / cs;
            lv2[k] = log2nu - log2f(cs);
        }
        par ^= 1;
    }
    __syncthreads();   // close out pending reads of redm before stats reuse

    // --- softmax row stats of raw logits (base-2): lraw2 = lk2 * EPS ---
    float tm[5];
#pragma unroll
    for (int n = 0; n < 5; n++){
        float l0 = lk2[n][0]*0.05f, l1 = lk2[n][1]*0.05f;
        float l2 = lk2[n][2]*0.05f, l3 = lk2[n][3]*0.05f;
        tm[n] = fmaxf(fmaxf(l0, l1), fmaxf(l2, l3));
    }
#pragma unroll
    for (int off = 1; off < 64; off <<= 1){
#pragma unroll
        for (int n = 0; n < 5; n++) tm[n] = fmaxf(tm[n], __shfl_xor(tm[n], off));
    }
    if (lane == 0){
#pragma unroll
        for (int n = 0; n < 5; n++) redm[0][w][n] = tm[n];
    }
    __syncthreads();
    float mx5[5];
#pragma unroll
    for (int n = 0; n < 5; n++){
        float gm = -1e30f;
        for (int i = 0; i < 16; i++) gm = fmaxf(gm, redm[0][i][n]);
        mx5[n] = gm;
    }
    float pz[5];
#pragma unroll
    for (int n = 0; n < 5; n++){
        pz[n] = exp2f(lk2[n][0]*0.05f - mx5[n]) + exp2f(lk2[n][1]*0.05f - mx5[n])
              + exp2f(lk2[n][2]*0.05f - mx5[n]) + exp2f(lk2[n][3]*0.05f - mx5[n]);
    }
#pragma unroll
    for (int off = 1; off < 64; off <<= 1){
#pragma unroll
        for (int n = 0; n < 5; n++) pz[n] += __shfl_xor(pz[n], off);
    }
    if (lane == 0){
#pragma unroll
        for (int n = 0; n < 5; n++) reds[w][n] = pz[n];
    }
    __syncthreads();
    float iz5[5];
#pragma unroll
    for (int n = 0; n < 5; n++){
        float z = 0.f;
        for (int i = 0; i < 16; i++) z += reds[i][n];
        iz5[n] = 1.0f / z;
    }
    // --- BCE(T, M) ---
    float acc = 0.f;
#pragma unroll
    for (int n = 0; n < 5; n++){
#pragma unroll
        for (int k = 0; k < 4; k++){
            float Mv = exp2f(lk2[n][k]*0.05f - mx5[n]) * iz5[n];
            float Mc = fminf(fmaxf(Mv, 1e-6f), 1.0f - 1e-6f);
            float lT2 = lu2[n] + lk2[n][k] + lv2[k];
            float T  = fminf(exp2f(lT2), 1.0f);
            acc -= (T * log2f(Mc) + (1.0f - T) * log2f(1.0f - Mc)) * LN2;
        }
    }
    acc = warpReduceSum(acc);
    if (lane == 0) redb[w] = acc;
    __syncthreads();
    if (t == 0){
        float s = 0.f;
        for (int i = 0; i < 16; i++) s += redb[i];
        atomicAdd(out_l, s * (1.0f / (16.0f * 5.0f * 4096.0f)));
    }
}

// ---------------------------------------------------------------------------
// K6: epilogue, one block per (b,n) row. 80 blocks x 512 threads.
// ---------------------------------------------------------------------------
__global__ __launch_bounds__(512) void k_epilogue(
    const float* __restrict__ A, const float* __restrict__ P1,
    const float* __restrict__ wvw, const float* __restrict__ wvb,
    const float* __restrict__ clns, const float* __restrict__ clnb,
    const float* __restrict__ w1, const float* __restrict__ b1,
    const float* __restrict__ w2, const float* __restrict__ b2,
    const float* __restrict__ flns, const float* __restrict__ flnb,
    float* __restrict__ out)
{
    __shared__ float Ar[256], P1r[256], P2[256], hl[512], parts[2][256], s8[8];
    int bn = blockIdx.x;
    int n = bn % 5;
    int t = threadIdx.x;
    if (t < 256){ Ar[t] = A[(size_t)bn*256 + t]; P1r[t] = P1[n*256 + t]; }
    __syncthreads();
    int c = t & 255, p = t >> 8;
    {
        float acc = 0.f;
        const float* wp = wvw + (size_t)(p*128)*256 + c;
#pragma unroll 16
        for (int k = 0; k < 128; k++) acc += Ar[p*128 + k] * wp[(size_t)k*256];
        parts[p][c] = acc;
    }
    __syncthreads();
    float x = 0.f;
    if (t < 256) x = P1r[t] + parts[0][t] + parts[1][t] + wvb[t];
    float sum  = blockSum512((t < 256) ? x : 0.f, s8);
    float mean = sum * (1.0f/256.0f);
    float d    = x - mean;
    float sq   = blockSum512((t < 256) ? d*d : 0.f, s8);
    float rstd = rsqrtf(sq * (1.0f/256.0f) + 1e-5f);
    float p2v = 0.f;
    if (t < 256){
        p2v = d * rstd * clns[t] + clnb[t];
        P2[t] = p2v;
    }
    __syncthreads();
    {
        float a = b1[t];
        const float* wp = w1 + t;
#pragma unroll 16
        for (int k = 0; k < 256; k++) a += P2[k] * wp[(size_t)k*512];
        hl[t] = 0.5f * a * (1.0f + erff(a * 0.70710678118654752f));
    }
    __syncthreads();
    {
        float acc = 0.f;
        const float* wp = w2 + (size_t)(p*256)*256 + c;
#pragma unroll 16
        for (int k = 0; k < 256; k++) acc += hl[p*256 + k] * wp[(size_t)k*256];
        parts[p][c] = acc;
    }
    __syncthreads();
    float x2 = 0.f;
    if (t < 256) x2 = P2[t] + parts[0][t] + parts[1][t] + b2[t];
    float sum2  = blockSum512((t < 256) ? x2 : 0.f, s8);
    float mean2 = sum2 * (1.0f/256.0f);
    float d2    = x2 - mean2;
    float sq2   = blockSum512((t < 256) ? d2*d2 : 0.f, s8);
    float rstd2 = rsqrtf(sq2 * (1.0f/256.0f) + 1e-5f);
    if (t < 256) out[(size_t)bn*256 + t] = d2 * rstd2 * flns[t] + flnb[t];
}

// ---------------------------------------------------------------------------
extern "C" void kernel_launch(void* const* d_in, const int* in_sizes, int n_in,
                              void* d_out, int out_size, void* d_ws, size_t ws_size,
                              hipStream_t stream)
{
    const float* Fd      = (const float*)d_in[0];
    const float* prompts = (const float*)d_in[1];
    const float* sa_q_w  = (const float*)d_in[2];
    const float* sa_q_b  = (const float*)d_in[3];
    const float* sa_k_w  = (const float*)d_in[4];
    const float* sa_k_b  = (const float*)d_in[5];
    const float* sa_v_w  = (const float*)d_in[6];
    const float* sa_v_b  = (const float*)d_in[7];
    const float* sa_ln_s = (const float*)d_in[8];
    const float* sa_ln_b = (const float*)d_in[9];
    const float* wq_w    = (const float*)d_in[10];
    const float* wq_b    = (const float*)d_in[11];
    const float* wk_w    = (const float*)d_in[12];
    const float* wk_b    = (const float*)d_in[13];
    const float* wv_w    = (const float*)d_in[14];
    const float* wv_b    = (const float*)d_in[15];
    const float* ca_ln_s = (const float*)d_in[16];
    const float* ca_ln_b = (const float*)d_in[17];
    const float* ffn_w1  = (const float*)d_in[18];
    const float* ffn_b1  = (const float*)d_in[19];
    const float* ffn_w2  = (const float*)d_in[20];
    const float* ffn_b2  = (const float*)d_in[21];
    const float* ffn_ln_s= (const float*)d_in[22];
    const float* ffn_ln_b= (const float*)d_in[23];

    float* out = (float*)d_out;
    float* ws  = (float*)d_ws;

    // workspace layout (floats)
    float* P1     = ws;            // 1280
    float* qkb    = ws + 1536;     // 5
    float* QKV    = ws + 2048;     // 3840
    float* u      = ws + 6144;     // 256
    float* bq2    = ws + 6400;     // 256
    float* qkg    = ws + 6656;     // 1280
    float* Wqk    = ws + 8192;     // 65536
    float* logits = ws + 73728;    // 327680
    float* Amat   = ws + 401408;   // 20480

    hipMemsetAsync(out + 20480, 0, sizeof(float), stream);

    k_weight<<<256, 256, 0, stream>>>(wq_w, wq_b, wk_w, wk_b, Wqk, u, bq2);
    k_qkv<<<12, 256, 0, stream>>>(prompts, sa_q_w, sa_q_b, sa_k_w, sa_k_b,
                                  sa_v_w, sa_v_b, QKV);
    k_attn<<<1, 256, 0, stream>>>(QKV, prompts, sa_ln_s, sa_ln_b, P1);
    k_qk<<<5, 256, 0, stream>>>(P1, Wqk, bq2, u, wq_b, wk_b, qkg, qkb);
    k_logits<<<dim3(16, 16), 256, 0, stream>>>(Fd, qkg, qkb, logits);
    k_A<<<dim3(16, 16), 1024, 0, stream>>>(Fd, logits, Amat);
    k_sinkhorn<<<16, 1024, 0, stream>>>(logits, out + 20480);
    k_epilogue<<<80, 512, 0, stream>>>(Amat, P1, wv_w, wv_b, ca_ln_s, ca_ln_b,
                                       ffn_w1, ffn_b1, ffn_w2, ffn_b2,
                                       ffn_ln_s, ffn_ln_b, out);
}

// Round 6
// 256.434 us; speedup vs baseline: 1.9010x; 1.2606x over previous
//
#include <hip/hip_runtime.h>
#include <hip/hip_fp16.h>
#include <math.h>

#define LOG2E 1.44269504088896340f
#define LN2   0.69314718055994531f

__device__ __forceinline__ float warpReduceSum(float v){
#pragma unroll
    for (int off = 32; off > 0; off >>= 1) v += __shfl_down(v, off);
    return v;
}
__device__ __forceinline__ float warpReduceMax(float v){
#pragma unroll
    for (int off = 32; off > 0; off >>= 1) v = fmaxf(v, __shfl_down(v, off));
    return v;
}

// block of 256 threads (4 waves)
__device__ float blockSum256(float v, float* s4){
    v = warpReduceSum(v);
    int w = threadIdx.x >> 6;
    __syncthreads();
    if ((threadIdx.x & 63) == 0) s4[w] = v;
    __syncthreads();
    return s4[0] + s4[1] + s4[2] + s4[3];
}
// block of 512 threads (8 waves)
__device__ float blockSum512(float v, float* s8){
    v = warpReduceSum(v);
    int w = threadIdx.x >> 6;
    __syncthreads();
    if ((threadIdx.x & 63) == 0) s8[w] = v;
    __syncthreads();
    float s = 0.f;
#pragma unroll
    for (int i = 0; i < 8; i++) s += s8[i];
    return s;
}

// ---------------------------------------------------------------------------
// K1: QKV projections of prompts. grid 12 blocks (3 mat x 4 col-chunks).
// ---------------------------------------------------------------------------
__global__ __launch_bounds__(256) void k_qkv(
    const float* __restrict__ prompts,
    const float* __restrict__ qw, const float* __restrict__ qb,
    const float* __restrict__ kw, const float* __restrict__ kb,
    const float* __restrict__ vw, const float* __restrict__ vb,
    float* __restrict__ QKV)
{
    __shared__ float Pl[1280];
    __shared__ float parts[4][5][64];
    int t = threadIdx.x;
    int mat = blockIdx.x >> 2, chunk = blockIdx.x & 3;
    for (int i = t; i < 1280; i += 256) Pl[i] = prompts[i];
    const float* W  = (mat == 0) ? qw : (mat == 1) ? kw : vw;
    const float* Bv = (mat == 0) ? qb : (mat == 1) ? kb : vb;
    int cl = t & 63, p = t >> 6;
    int col = chunk*64 + cl;
    __syncthreads();
    float acc[5] = {0,0,0,0,0};
    const float* wp = W + (size_t)(p*64)*256 + col;
#pragma unroll 8
    for (int c = 0; c < 64; c++){
        float wv = wp[(size_t)c*256];
#pragma unroll
        for (int n = 0; n < 5; n++) acc[n] += Pl[n*256 + p*64 + c] * wv;
    }
#pragma unroll
    for (int n = 0; n < 5; n++) parts[p][n][cl] = acc[n];
    __syncthreads();
    // 320 outputs, 256 threads -> strided
    for (int i = t; i < 320; i += 256){
        int n = i >> 6, c2 = i & 63;
        float s = parts[0][n][c2] + parts[1][n][c2] + parts[2][n][c2] + parts[3][n][c2]
                + Bv[chunk*64 + c2];
        QKV[mat*1280 + n*256 + chunk*64 + c2] = s;
    }
}

// ---------------------------------------------------------------------------
// K2: prompt self-attention + LN -> P1. 1 block x 256 threads (small only).
// ---------------------------------------------------------------------------
__global__ __launch_bounds__(256) void k_attn(
    const float* __restrict__ QKV, const float* __restrict__ prompts,
    const float* __restrict__ lns, const float* __restrict__ lnb,
    float* __restrict__ P1g)
{
    __shared__ float Pl[1280], Ql[1280], Kl[1280], Vl[1280], Sl[25], s4[4];
    int t = threadIdx.x;
    for (int i = t; i < 1280; i += 256){
        Pl[i] = prompts[i];
        Ql[i] = QKV[i];
        Kl[i] = QKV[1280 + i];
        Vl[i] = QKV[2560 + i];
    }
    __syncthreads();
    if (t < 25){
        int n = t / 5, m = t % 5;
        float s = 0.f;
        for (int c = 0; c < 256; c++) s += Ql[n*256 + c] * Kl[m*256 + c];
        Sl[t] = s * 0.0625f;
    }
    __syncthreads();
    if (t < 5){
        float mx = -1e30f;
        for (int m = 0; m < 5; m++) mx = fmaxf(mx, Sl[t*5 + m]);
        float e[5], sm = 0.f;
        for (int m = 0; m < 5; m++){ e[m] = expf(Sl[t*5 + m] - mx); sm += e[m]; }
        for (int m = 0; m < 5; m++) Sl[t*5 + m] = e[m] / sm;
    }
    __syncthreads();
    float x[5];
#pragma unroll
    for (int n = 0; n < 5; n++){
        float s = 0.f;
        for (int m = 0; m < 5; m++) s += Sl[n*5 + m] * Vl[m*256 + t];
        x[n] = Pl[n*256 + t] + s;
    }
#pragma unroll
    for (int n = 0; n < 5; n++){
        float sum  = blockSum256(x[n], s4);
        float mean = sum * (1.0f/256.0f);
        float d    = x[n] - mean;
        float sq   = blockSum256(d*d, s4);
        float rstd = rsqrtf(sq * (1.0f/256.0f) + 1e-5f);
        P1g[n*256 + t] = d * rstd * lns[t] + lnb[t];
    }
}

// ---------------------------------------------------------------------------
// K2b: Qc[n][d] = sum_e P1[n][e]*wq_w[e][d] + wq_b[d].  5 blocks x 256 thr.
// ---------------------------------------------------------------------------
__global__ __launch_bounds__(256) void k_qc(
    const float* __restrict__ P1, const float* __restrict__ wqw,
    const float* __restrict__ wqb, float* __restrict__ Qcg)
{
    __shared__ float Pr[256];
    int n = blockIdx.x, t = threadIdx.x;
    Pr[t] = P1[n*256 + t];
    __syncthreads();
    float acc = wqb[t];
    const float* wp = wqw + t;
#pragma unroll 16
    for (int d = 0; d < 256; d++) acc += Pr[d] * wp[(size_t)d*256];
    Qcg[n*256 + t] = acc;
}

// ---------------------------------------------------------------------------
// K2c: qk[n][c] = sum_d Qc[n][d]*wk_w[c][d];  qkb[n] = Qc[n].wk_b.
// grid (16,5) x 256 threads. Wave w handles c = bx*16 + w*4 + {0..3};
// lanes reduce over d (coalesced 256B reads of wk_w row).
// ---------------------------------------------------------------------------
__global__ __launch_bounds__(256) void k_qk2(
    const float* __restrict__ Qc, const float* __restrict__ wkw,
    const float* __restrict__ wkb,
    float* __restrict__ qkg, float* __restrict__ qkbg)
{
    __shared__ float Qr[256], s4[4];
    int n = blockIdx.y, t = threadIdx.x;
    int w = t >> 6, lane = t & 63;
    Qr[t] = Qc[n*256 + t];
    __syncthreads();
#pragma unroll
    for (int i = 0; i < 4; i++){
        int c = blockIdx.x*16 + w*4 + i;
        const float* kp = wkw + (size_t)c*256;
        float acc = Qr[lane]       * kp[lane]
                  + Qr[lane + 64]  * kp[lane + 64]
                  + Qr[lane + 128] * kp[lane + 128]
                  + Qr[lane + 192] * kp[lane + 192];
#pragma unroll
        for (int off = 1; off < 64; off <<= 1) acc += __shfl_xor(acc, off);
        if (lane == 0) qkg[n*256 + c] = acc;
    }
    if (blockIdx.x == 0){
        float pu = blockSum256(Qr[t] * wkb[t], s4);
        if (t == 0) qkbg[n] = pu;
    }
}

// ---------------------------------------------------------------------------
// K3: logits[b,n,m] = scale*(qk[n,:].Fd[b,:,m] + qkb[n]).
// grid (16,16) x 1024 threads: 4-way c-split (p = t>>8) for TLP on the cold
// Fd stream; partials combined through LDS.
// ---------------------------------------------------------------------------
__global__ __launch_bounds__(1024) void k_logits(
    const float* __restrict__ Fd, const float* __restrict__ qkg,
    const float* __restrict__ qkbg, float* __restrict__ logits)
{
    __shared__ float qk[1280];
    __shared__ float qb5[5];
    __shared__ float parts[4][5][256];
    int t = threadIdx.x;
    for (int i = t; i < 1280; i += 1024) qk[i] = qkg[i];
    if (t < 5) qb5[t] = qkbg[t];
    __syncthreads();
    int b = blockIdx.y;
    int p = t >> 8, ml = t & 255;
    int m = blockIdx.x * 256 + ml;
    const float* fp = Fd + ((size_t)(b*256 + p*64)) * 4096 + m;
    float a0 = 0.f, a1 = 0.f, a2 = 0.f, a3 = 0.f, a4 = 0.f;
#pragma unroll 16
    for (int c = 0; c < 64; c++){
        float f = fp[(size_t)c * 4096];
        a0 += qk[          p*64 + c] * f;
        a1 += qk[256  +    p*64 + c] * f;
        a2 += qk[512  +    p*64 + c] * f;
        a3 += qk[768  +    p*64 + c] * f;
        a4 += qk[1024 +    p*64 + c] * f;
    }
    parts[p][0][ml] = a0; parts[p][1][ml] = a1; parts[p][2][ml] = a2;
    parts[p][3][ml] = a3; parts[p][4][ml] = a4;
    __syncthreads();
    for (int i = t; i < 1280; i += 1024){
        int n = i >> 8, mm = i & 255;
        float s = parts[0][n][mm] + parts[1][n][mm] + parts[2][n][mm] + parts[3][n][mm]
                + qb5[n];
        logits[((size_t)(b*5) + n)*4096 + blockIdx.x*256 + mm] = s * 0.0625f;
    }
}

// ---------------------------------------------------------------------------
// K4: A[b,n,c] = sum_m softmax(logits[b,n,:])[m] * Fd[b,c,m]
// grid (cc=16, b=16) x 1024. M staged in LDS as __half (40KB).
// ---------------------------------------------------------------------------
__global__ __launch_bounds__(1024) void k_A(
    const float* __restrict__ Fd, const float* __restrict__ logits,
    float* __restrict__ A)
{
    __shared__ __align__(16) __half Ml[5*4096];
    __shared__ float red[80];
    int b = blockIdx.y, cc = blockIdx.x, t = threadIdx.x;
    int w = t >> 6, lane = t & 63;
    const float* Lb = logits + (size_t)(b*5) * 4096;
    float ll[5][4];
#pragma unroll
    for (int n = 0; n < 5; n++)
#pragma unroll
        for (int k = 0; k < 4; k++)
            ll[n][k] = Lb[n*4096 + t + k*1024];
#pragma unroll
    for (int n = 0; n < 5; n++){
        float tm = fmaxf(fmaxf(ll[n][0], ll[n][1]), fmaxf(ll[n][2], ll[n][3]));
        tm = warpReduceMax(tm);
        if (lane == 0) red[w*5 + n] = tm;
    }
    __syncthreads();
    float mx[5];
#pragma unroll
    for (int n = 0; n < 5; n++){
        float gm = -1e30f;
        for (int i = 0; i < 16; i++) gm = fmaxf(gm, red[i*5 + n]);
        mx[n] = gm;
    }
    __syncthreads();
    float e[5][4];
#pragma unroll
    for (int n = 0; n < 5; n++){
        float ps = 0.f;
#pragma unroll
        for (int k = 0; k < 4; k++){ e[n][k] = expf(ll[n][k] - mx[n]); ps += e[n][k]; }
        ps = warpReduceSum(ps);
        if (lane == 0) red[w*5 + n] = ps;
    }
    __syncthreads();
#pragma unroll
    for (int n = 0; n < 5; n++){
        float z = 0.f;
        for (int i = 0; i < 16; i++) z += red[i*5 + n];
        float inv = 1.0f / z;
#pragma unroll
        for (int k = 0; k < 4; k++)
            Ml[n*4096 + t + k*1024] = __float2half(e[n][k] * inv);
    }
    __syncthreads();
    int c = cc*16 + w;
    const float* fp = Fd + ((size_t)(b*256 + c)) * 4096;
    float4 a4[5];
#pragma unroll
    for (int n = 0; n < 5; n++) a4[n] = make_float4(0.f, 0.f, 0.f, 0.f);
#pragma unroll 4
    for (int it = 0; it < 16; it++){
        int m4 = it*256 + (lane << 2);
        float4 f = *(const float4*)(fp + m4);
#pragma unroll
        for (int n = 0; n < 5; n++){
            const __half2* mp = (const __half2*)(Ml + n*4096 + m4);
            float2 m0 = __half22float2(mp[0]);
            float2 m1 = __half22float2(mp[1]);
            a4[n].x += m0.x * f.x; a4[n].y += m0.y * f.y;
            a4[n].z += m1.x * f.z; a4[n].w += m1.y * f.w;
        }
    }
#pragma unroll
    for (int n = 0; n < 5; n++){
        float s = a4[n].x + a4[n].y + a4[n].z + a4[n].w;
        s = warpReduceSum(s);
        if (lane == 0) A[(size_t)(b*5 + n)*256 + c] = s;
    }
}

// ---------------------------------------------------------------------------
// K5: per-batch Sinkhorn + BCE, LINEAR domain. 16 blocks x 1024 threads.
// ---------------------------------------------------------------------------
__global__ __launch_bounds__(1024) void k_sinkhorn(
    const float* __restrict__ logits, float* __restrict__ out_l)
{
    __shared__ float redm[2][16][5], reds[16][5];
    __shared__ float redb[16];
    int b = blockIdx.x, t = threadIdx.x;
    int w = t >> 6, lane = t & 63;
    const float* Lb = logits + (size_t)b * 5 * 4096;
    float lk2[5][4], ek[5][4];
#pragma unroll
    for (int n = 0; n < 5; n++)
#pragma unroll
        for (int k = 0; k < 4; k++){
            float lv = (Lb[n*4096 + t + k*1024] / 0.05f) * LOG2E;  // log2 K
            lk2[n][k] = lv;
            ek[n][k] = exp2f(lv);
        }
    const float mu_lin  = 0.2f + 1e-8f;
    const float nu_lin  = 1.0f/4096.0f + 1e-8f;
    const float log2mu  = log2f(mu_lin);
    const float log2nu  = log2f(nu_lin);
    const float TOL2    = 1e-4f * LOG2E;   // TOL in log2 units

    float vv[4]  = {1.f, 1.f, 1.f, 1.f};
    float lu2[5] = {0,0,0,0,0};
    float lv2[4] = {0,0,0,0};
    float en[5];
    float diff = 1e30f;
    int par = 0;

    for (int it = 0; it < 100; ++it){
        if (diff < TOL2) break;
        float gs[5];
#pragma unroll
        for (int n = 0; n < 5; n++)
            gs[n] = ek[n][0]*vv[0] + ek[n][1]*vv[1] + ek[n][2]*vv[2] + ek[n][3]*vv[3];
#pragma unroll
        for (int off = 1; off < 64; off <<= 1){
#pragma unroll
            for (int n = 0; n < 5; n++) gs[n] += __shfl_xor(gs[n], off);
        }
        if (lane == 0){
#pragma unroll
            for (int n = 0; n < 5; n++) redm[par][w][n] = gs[n];
        }
        __syncthreads();
        float nd = 0.f;
#pragma unroll
        for (int n = 0; n < 5; n++){
            float s = 0.f;
            for (int i = 0; i < 16; i++) s += redm[par][i][n];
            float nl = log2mu - log2f(s);
            nd = fmaxf(nd, fabsf(nl - lu2[n]));
            lu2[n] = nl;
            en[n] = mu_lin / s;
        }
        diff = nd;
#pragma unroll
        for (int k = 0; k < 4; k++){
            float cs = ek[0][k]*en[0] + ek[1][k]*en[1] + ek[2][k]*en[2]
                     + ek[3][k]*en[3] + ek[4][k]*en[4];
            vv[k]  = nu_lin / cs;
            lv2[k] = log2nu - log2f(cs);
        }
        par ^= 1;
    }
    __syncthreads();

    // --- softmax row stats of raw logits (base-2): lraw2 = lk2 * EPS ---
    float tm[5];
#pragma unroll
    for (int n = 0; n < 5; n++){
        float l0 = lk2[n][0]*0.05f, l1 = lk2[n][1]*0.05f;
        float l2 = lk2[n][2]*0.05f, l3 = lk2[n][3]*0.05f;
        tm[n] = fmaxf(fmaxf(l0, l1), fmaxf(l2, l3));
    }
#pragma unroll
    for (int off = 1; off < 64; off <<= 1){
#pragma unroll
        for (int n = 0; n < 5; n++) tm[n] = fmaxf(tm[n], __shfl_xor(tm[n], off));
    }
    if (lane == 0){
#pragma unroll
        for (int n = 0; n < 5; n++) redm[0][w][n] = tm[n];
    }
    __syncthreads();
    float mx5[5];
#pragma unroll
    for (int n = 0; n < 5; n++){
        float gm = -1e30f;
        for (int i = 0; i < 16; i++) gm = fmaxf(gm, redm[0][i][n]);
        mx5[n] = gm;
    }
    float pz[5];
#pragma unroll
    for (int n = 0; n < 5; n++){
        pz[n] = exp2f(lk2[n][0]*0.05f - mx5[n]) + exp2f(lk2[n][1]*0.05f - mx5[n])
              + exp2f(lk2[n][2]*0.05f - mx5[n]) + exp2f(lk2[n][3]*0.05f - mx5[n]);
    }
#pragma unroll
    for (int off = 1; off < 64; off <<= 1){
#pragma unroll
        for (int n = 0; n < 5; n++) pz[n] += __shfl_xor(pz[n], off);
    }
    if (lane == 0){
#pragma unroll
        for (int n = 0; n < 5; n++) reds[w][n] = pz[n];
    }
    __syncthreads();
    float iz5[5];
#pragma unroll
    for (int n = 0; n < 5; n++){
        float z = 0.f;
        for (int i = 0; i < 16; i++) z += reds[i][n];
        iz5[n] = 1.0f / z;
    }
    // --- BCE(T, M) ---
    float acc = 0.f;
#pragma unroll
    for (int n = 0; n < 5; n++){
#pragma unroll
        for (int k = 0; k < 4; k++){
            float Mv = exp2f(lk2[n][k]*0.05f - mx5[n]) * iz5[n];
            float Mc = fminf(fmaxf(Mv, 1e-6f), 1.0f - 1e-6f);
            float lT2 = lu2[n] + lk2[n][k] + lv2[k];
            float T  = fminf(exp2f(lT2), 1.0f);
            acc -= (T * log2f(Mc) + (1.0f - T) * log2f(1.0f - Mc)) * LN2;
        }
    }
    acc = warpReduceSum(acc);
    if (lane == 0) redb[w] = acc;
    __syncthreads();
    if (t == 0){
        float s = 0.f;
        for (int i = 0; i < 16; i++) s += redb[i];
        atomicAdd(out_l, s * (1.0f / (16.0f * 5.0f * 4096.0f)));
    }
}

// ---------------------------------------------------------------------------
// K6: epilogue, one block per (b,n) row. 80 blocks x 512 threads.
// ---------------------------------------------------------------------------
__global__ __launch_bounds__(512) void k_epilogue(
    const float* __restrict__ A, const float* __restrict__ P1,
    const float* __restrict__ wvw, const float* __restrict__ wvb,
    const float* __restrict__ clns, const float* __restrict__ clnb,
    const float* __restrict__ w1, const float* __restrict__ b1,
    const float* __restrict__ w2, const float* __restrict__ b2,
    const float* __restrict__ flns, const float* __restrict__ flnb,
    float* __restrict__ out)
{
    __shared__ float Ar[256], P1r[256], P2[256], hl[512], parts[2][256], s8[8];
    int bn = blockIdx.x;
    int n = bn % 5;
    int t = threadIdx.x;
    if (t < 256){ Ar[t] = A[(size_t)bn*256 + t]; P1r[t] = P1[n*256 + t]; }
    __syncthreads();
    int c = t & 255, p = t >> 8;
    {
        float acc = 0.f;
        const float* wp = wvw + (size_t)(p*128)*256 + c;
#pragma unroll 16
        for (int k = 0; k < 128; k++) acc += Ar[p*128 + k] * wp[(size_t)k*256];
        parts[p][c] = acc;
    }
    __syncthreads();
    float x = 0.f;
    if (t < 256) x = P1r[t] + parts[0][t] + parts[1][t] + wvb[t];
    float sum  = blockSum512((t < 256) ? x : 0.f, s8);
    float mean = sum * (1.0f/256.0f);
    float d    = x - mean;
    float sq   = blockSum512((t < 256) ? d*d : 0.f, s8);
    float rstd = rsqrtf(sq * (1.0f/256.0f) + 1e-5f);
    float p2v = 0.f;
    if (t < 256){
        p2v = d * rstd * clns[t] + clnb[t];
        P2[t] = p2v;
    }
    __syncthreads();
    {
        float a = b1[t];
        const float* wp = w1 + t;
#pragma unroll 16
        for (int k = 0; k < 256; k++) a += P2[k] * wp[(size_t)k*512];
        hl[t] = 0.5f * a * (1.0f + erff(a * 0.70710678118654752f));
    }
    __syncthreads();
    {
        float acc = 0.f;
        const float* wp = w2 + (size_t)(p*256)*256 + c;
#pragma unroll 16
        for (int k = 0; k < 256; k++) acc += hl[p*256 + k] * wp[(size_t)k*256];
        parts[p][c] = acc;
    }
    __syncthreads();
    float x2 = 0.f;
    if (t < 256) x2 = P2[t] + parts[0][t] + parts[1][t] + b2[t];
    float sum2  = blockSum512((t < 256) ? x2 : 0.f, s8);
    float mean2 = sum2 * (1.0f/256.0f);
    float d2    = x2 - mean2;
    float sq2   = blockSum512((t < 256) ? d2*d2 : 0.f, s8);
    float rstd2 = rsqrtf(sq2 * (1.0f/256.0f) + 1e-5f);
    if (t < 256) out[(size_t)bn*256 + t] = d2 * rstd2 * flns[t] + flnb[t];
}

// ---------------------------------------------------------------------------
extern "C" void kernel_launch(void* const* d_in, const int* in_sizes, int n_in,
                              void* d_out, int out_size, void* d_ws, size_t ws_size,
                              hipStream_t stream)
{
    const float* Fd      = (const float*)d_in[0];
    const float* prompts = (const float*)d_in[1];
    const float* sa_q_w  = (const float*)d_in[2];
    const float* sa_q_b  = (const float*)d_in[3];
    const float* sa_k_w  = (const float*)d_in[4];
    const float* sa_k_b  = (const float*)d_in[5];
    const float* sa_v_w  = (const float*)d_in[6];
    const float* sa_v_b  = (const float*)d_in[7];
    const float* sa_ln_s = (const float*)d_in[8];
    const float* sa_ln_b = (const float*)d_in[9];
    const float* wq_w    = (const float*)d_in[10];
    const float* wq_b    = (const float*)d_in[11];
    const float* wk_w    = (const float*)d_in[12];
    const float* wk_b    = (const float*)d_in[13];
    const float* wv_w    = (const float*)d_in[14];
    const float* wv_b    = (const float*)d_in[15];
    const float* ca_ln_s = (const float*)d_in[16];
    const float* ca_ln_b = (const float*)d_in[17];
    const float* ffn_w1  = (const float*)d_in[18];
    const float* ffn_b1  = (const float*)d_in[19];
    const float* ffn_w2  = (const float*)d_in[20];
    const float* ffn_b2  = (const float*)d_in[21];
    const float* ffn_ln_s= (const float*)d_in[22];
    const float* ffn_ln_b= (const float*)d_in[23];

    float* out = (float*)d_out;
    float* ws  = (float*)d_ws;

    // workspace layout (floats)
    float* P1     = ws;            // 1280
    float* qkb    = ws + 1536;     // 5
    float* QKV    = ws + 2048;     // 3840
    float* Qc     = ws + 6144;     // 1280
    float* qkg    = ws + 8192;     // 1280
    float* logits = ws + 73728;    // 327680
    float* Amat   = ws + 401408;   // 20480

    hipMemsetAsync(out + 20480, 0, sizeof(float), stream);

    k_qkv<<<12, 256, 0, stream>>>(prompts, sa_q_w, sa_q_b, sa_k_w, sa_k_b,
                                  sa_v_w, sa_v_b, QKV);
    k_attn<<<1, 256, 0, stream>>>(QKV, prompts, sa_ln_s, sa_ln_b, P1);
    k_qc<<<5, 256, 0, stream>>>(P1, wq_w, wq_b, Qc);
    k_qk2<<<dim3(16, 5), 256, 0, stream>>>(Qc, wk_w, wk_b, qkg, qkb);
    k_logits<<<dim3(16, 16), 1024, 0, stream>>>(Fd, qkg, qkb, logits);
    k_A<<<dim3(16, 16), 1024, 0, stream>>>(Fd, logits, Amat);
    k_sinkhorn<<<16, 1024, 0, stream>>>(logits, out + 20480);
    k_epilogue<<<80, 512, 0, stream>>>(Amat, P1, wv_w, wv_b, ca_ln_s, ca_ln_b,
                                       ffn_w1, ffn_b1, ffn_w2, ffn_b2,
                                       ffn_ln_s, ffn_ln_b, out);
}

// Round 7
// 247.084 us; speedup vs baseline: 1.9730x; 1.0378x over previous
//
#include <hip/hip_runtime.h>
#include <hip/hip_fp16.h>
#include <math.h>

#define LOG2E 1.44269504088896340f
#define LN2   0.69314718055994531f

__device__ __forceinline__ float warpReduceSum(float v){
#pragma unroll
    for (int off = 32; off > 0; off >>= 1) v += __shfl_down(v, off);
    return v;
}
__device__ __forceinline__ float warpReduceMax(float v){
#pragma unroll
    for (int off = 32; off > 0; off >>= 1) v = fmaxf(v, __shfl_down(v, off));
    return v;
}

// block of 256 threads (4 waves)
__device__ float blockSum256(float v, float* s4){
    v = warpReduceSum(v);
    int w = threadIdx.x >> 6;
    __syncthreads();
    if ((threadIdx.x & 63) == 0) s4[w] = v;
    __syncthreads();
    return s4[0] + s4[1] + s4[2] + s4[3];
}
// block of 512 threads (8 waves)
__device__ float blockSum512(float v, float* s8){
    v = warpReduceSum(v);
    int w = threadIdx.x >> 6;
    __syncthreads();
    if ((threadIdx.x & 63) == 0) s8[w] = v;
    __syncthreads();
    float s = 0.f;
#pragma unroll
    for (int i = 0; i < 8; i++) s += s8[i];
    return s;
}

// ---------------------------------------------------------------------------
// K1: QKV projections of prompts. grid 12 blocks (3 mat x 4 col-chunks).
// ---------------------------------------------------------------------------
__global__ __launch_bounds__(256) void k_qkv(
    const float* __restrict__ prompts,
    const float* __restrict__ qw, const float* __restrict__ qb,
    const float* __restrict__ kw, const float* __restrict__ kb,
    const float* __restrict__ vw, const float* __restrict__ vb,
    float* __restrict__ QKV)
{
    __shared__ float Pl[1280];
    __shared__ float parts[4][5][64];
    int t = threadIdx.x;
    int mat = blockIdx.x >> 2, chunk = blockIdx.x & 3;
    for (int i = t; i < 1280; i += 256) Pl[i] = prompts[i];
    const float* W  = (mat == 0) ? qw : (mat == 1) ? kw : vw;
    const float* Bv = (mat == 0) ? qb : (mat == 1) ? kb : vb;
    int cl = t & 63, p = t >> 6;
    int col = chunk*64 + cl;
    __syncthreads();
    float acc[5] = {0,0,0,0,0};
    const float* wp = W + (size_t)(p*64)*256 + col;
#pragma unroll 8
    for (int c = 0; c < 64; c++){
        float wv = wp[(size_t)c*256];
#pragma unroll
        for (int n = 0; n < 5; n++) acc[n] += Pl[n*256 + p*64 + c] * wv;
    }
#pragma unroll
    for (int n = 0; n < 5; n++) parts[p][n][cl] = acc[n];
    __syncthreads();
    for (int i = t; i < 320; i += 256){
        int n = i >> 6, c2 = i & 63;
        float s = parts[0][n][c2] + parts[1][n][c2] + parts[2][n][c2] + parts[3][n][c2]
                + Bv[chunk*64 + c2];
        QKV[mat*1280 + n*256 + chunk*64 + c2] = s;
    }
}

// ---------------------------------------------------------------------------
// K2: prompt self-attention + LN -> P1, fused with Qc. grid 5 x 256.
// All 5 blocks redundantly compute the tiny attention; block n emits Qc[n].
// ---------------------------------------------------------------------------
__global__ __launch_bounds__(256) void k_attn_qc(
    const float* __restrict__ QKV, const float* __restrict__ prompts,
    const float* __restrict__ lns, const float* __restrict__ lnb,
    const float* __restrict__ wqw, const float* __restrict__ wqb,
    float* __restrict__ P1g, float* __restrict__ Qcg)
{
    __shared__ float Pl[1280], Ql[1280], Kl[1280], Vl[1280], Sl[25], s4[4];
    int t = threadIdx.x;
    for (int i = t; i < 1280; i += 256){
        Pl[i] = prompts[i];
        Ql[i] = QKV[i];
        Kl[i] = QKV[1280 + i];
        Vl[i] = QKV[2560 + i];
    }
    __syncthreads();
    if (t < 25){
        int n = t / 5, m = t % 5;
        float s = 0.f;
        for (int c = 0; c < 256; c++) s += Ql[n*256 + c] * Kl[m*256 + c];
        Sl[t] = s * 0.0625f;
    }
    __syncthreads();
    if (t < 5){
        float mx = -1e30f;
        for (int m = 0; m < 5; m++) mx = fmaxf(mx, Sl[t*5 + m]);
        float e[5], sm = 0.f;
        for (int m = 0; m < 5; m++){ e[m] = expf(Sl[t*5 + m] - mx); sm += e[m]; }
        for (int m = 0; m < 5; m++) Sl[t*5 + m] = e[m] / sm;
    }
    __syncthreads();
    float x[5];
#pragma unroll
    for (int n = 0; n < 5; n++){
        float s = 0.f;
        for (int m = 0; m < 5; m++) s += Sl[n*5 + m] * Vl[m*256 + t];
        x[n] = Pl[n*256 + t] + s;
    }
#pragma unroll
    for (int n = 0; n < 5; n++){
        float sum  = blockSum256(x[n], s4);
        float mean = sum * (1.0f/256.0f);
        float d    = x[n] - mean;
        float sq   = blockSum256(d*d, s4);
        float rstd = rsqrtf(sq * (1.0f/256.0f) + 1e-5f);
        float y = d * rstd * lns[t] + lnb[t];
        Pl[n*256 + t] = y;
        if (blockIdx.x == 0) P1g[n*256 + t] = y;
    }
    __syncthreads();
    // Qc for row n = blockIdx.x
    int n = blockIdx.x;
    float acc = wqb[t];
    const float* wp = wqw + t;
#pragma unroll 16
    for (int d = 0; d < 256; d++) acc += Pl[n*256 + d] * wp[(size_t)d*256];
    Qcg[n*256 + t] = acc;
}

// ---------------------------------------------------------------------------
// K2c: qk[n][c] = sum_d Qc[n][d]*wk_w[c][d];  qkb[n] = Qc[n].wk_b.
// grid (16,5) x 256 threads.
// ---------------------------------------------------------------------------
__global__ __launch_bounds__(256) void k_qk2(
    const float* __restrict__ Qc, const float* __restrict__ wkw,
    const float* __restrict__ wkb,
    float* __restrict__ qkg, float* __restrict__ qkbg)
{
    __shared__ float Qr[256], s4[4];
    int n = blockIdx.y, t = threadIdx.x;
    int w = t >> 6, lane = t & 63;
    Qr[t] = Qc[n*256 + t];
    __syncthreads();
#pragma unroll
    for (int i = 0; i < 4; i++){
        int c = blockIdx.x*16 + w*4 + i;
        const float* kp = wkw + (size_t)c*256;
        float acc = Qr[lane]       * kp[lane]
                  + Qr[lane + 64]  * kp[lane + 64]
                  + Qr[lane + 128] * kp[lane + 128]
                  + Qr[lane + 192] * kp[lane + 192];
#pragma unroll
        for (int off = 1; off < 64; off <<= 1) acc += __shfl_xor(acc, off);
        if (lane == 0) qkg[n*256 + c] = acc;
    }
    if (blockIdx.x == 0){
        float pu = blockSum256(Qr[t] * wkb[t], s4);
        if (t == 0) qkbg[n] = pu;
    }
}

// ---------------------------------------------------------------------------
// K3: logits[b,n,m] = scale*(qk[n,:].Fd[b,:,m] + qkb[n]).
// grid (16,16) x 1024 threads: 4-way c-split for TLP on the cold Fd stream.
// ---------------------------------------------------------------------------
__global__ __launch_bounds__(1024) void k_logits(
    const float* __restrict__ Fd, const float* __restrict__ qkg,
    const float* __restrict__ qkbg, float* __restrict__ logits)
{
    __shared__ float qk[1280];
    __shared__ float qb5[5];
    __shared__ float parts[4][5][256];
    int t = threadIdx.x;
    for (int i = t; i < 1280; i += 1024) qk[i] = qkg[i];
    if (t < 5) qb5[t] = qkbg[t];
    __syncthreads();
    int b = blockIdx.y;
    int p = t >> 8, ml = t & 255;
    int m = blockIdx.x * 256 + ml;
    const float* fp = Fd + ((size_t)(b*256 + p*64)) * 4096 + m;
    float a0 = 0.f, a1 = 0.f, a2 = 0.f, a3 = 0.f, a4 = 0.f;
#pragma unroll 16
    for (int c = 0; c < 64; c++){
        float f = fp[(size_t)c * 4096];
        a0 += qk[          p*64 + c] * f;
        a1 += qk[256  +    p*64 + c] * f;
        a2 += qk[512  +    p*64 + c] * f;
        a3 += qk[768  +    p*64 + c] * f;
        a4 += qk[1024 +    p*64 + c] * f;
    }
    parts[p][0][ml] = a0; parts[p][1][ml] = a1; parts[p][2][ml] = a2;
    parts[p][3][ml] = a3; parts[p][4][ml] = a4;
    __syncthreads();
    for (int i = t; i < 1280; i += 1024){
        int n = i >> 8, mm = i & 255;
        float s = parts[0][n][mm] + parts[1][n][mm] + parts[2][n][mm] + parts[3][n][mm]
                + qb5[n];
        logits[((size_t)(b*5) + n)*4096 + blockIdx.x*256 + mm] = s * 0.0625f;
    }
}

// ---------------------------------------------------------------------------
// K4: A[b,n,c] = sum_m softmax(logits[b,n,:])[m] * Fd[b,c,m]
// grid (cc=16, b=16) x 1024. M staged in LDS as __half (40KB).
// ---------------------------------------------------------------------------
__global__ __launch_bounds__(1024) void k_A(
    const float* __restrict__ Fd, const float* __restrict__ logits,
    float* __restrict__ A)
{
    __shared__ __align__(16) __half Ml[5*4096];
    __shared__ float red[80];
    int b = blockIdx.y, cc = blockIdx.x, t = threadIdx.x;
    int w = t >> 6, lane = t & 63;
    const float* Lb = logits + (size_t)(b*5) * 4096;
    float ll[5][4];
#pragma unroll
    for (int n = 0; n < 5; n++)
#pragma unroll
        for (int k = 0; k < 4; k++)
            ll[n][k] = Lb[n*4096 + t + k*1024];
#pragma unroll
    for (int n = 0; n < 5; n++){
        float tm = fmaxf(fmaxf(ll[n][0], ll[n][1]), fmaxf(ll[n][2], ll[n][3]));
        tm = warpReduceMax(tm);
        if (lane == 0) red[w*5 + n] = tm;
    }
    __syncthreads();
    float mx[5];
#pragma unroll
    for (int n = 0; n < 5; n++){
        float gm = -1e30f;
        for (int i = 0; i < 16; i++) gm = fmaxf(gm, red[i*5 + n]);
        mx[n] = gm;
    }
    __syncthreads();
    float e[5][4];
#pragma unroll
    for (int n = 0; n < 5; n++){
        float ps = 0.f;
#pragma unroll
        for (int k = 0; k < 4; k++){ e[n][k] = expf(ll[n][k] - mx[n]); ps += e[n][k]; }
        ps = warpReduceSum(ps);
        if (lane == 0) red[w*5 + n] = ps;
    }
    __syncthreads();
#pragma unroll
    for (int n = 0; n < 5; n++){
        float z = 0.f;
        for (int i = 0; i < 16; i++) z += red[i*5 + n];
        float inv = 1.0f / z;
#pragma unroll
        for (int k = 0; k < 4; k++)
            Ml[n*4096 + t + k*1024] = __float2half(e[n][k] * inv);
    }
    __syncthreads();
    int c = cc*16 + w;
    const float* fp = Fd + ((size_t)(b*256 + c)) * 4096;
    float4 a4[5];
#pragma unroll
    for (int n = 0; n < 5; n++) a4[n] = make_float4(0.f, 0.f, 0.f, 0.f);
#pragma unroll 4
    for (int it = 0; it < 16; it++){
        int m4 = it*256 + (lane << 2);
        float4 f = *(const float4*)(fp + m4);
#pragma unroll
        for (int n = 0; n < 5; n++){
            const __half2* mp = (const __half2*)(Ml + n*4096 + m4);
            float2 m0 = __half22float2(mp[0]);
            float2 m1 = __half22float2(mp[1]);
            a4[n].x += m0.x * f.x; a4[n].y += m0.y * f.y;
            a4[n].z += m1.x * f.z; a4[n].w += m1.y * f.w;
        }
    }
#pragma unroll
    for (int n = 0; n < 5; n++){
        float s = a4[n].x + a4[n].y + a4[n].z + a4[n].w;
        s = warpReduceSum(s);
        if (lane == 0) A[(size_t)(b*5 + n)*256 + c] = s;
    }
}

// ---------------------------------------------------------------------------
// K5: per-batch Sinkhorn + BCE, fully linear (no logs in the loop).
// 16 blocks x 1024 threads. Convergence: lu_i = ln(en_i), so
// |lu_i - lu_{i-1}| < TOL  <=>  |en_i - en_prev| <= ~TOL * en_prev.
// T = u K v = en*ek*vv computed linearly. Partials written to `partial[b]`
// (summed by k_epilogue block 0 -> no memset launch needed).
// ---------------------------------------------------------------------------
__global__ __launch_bounds__(1024) void k_sinkhorn(
    const float* __restrict__ logits, float* __restrict__ partial)
{
    __shared__ __align__(16) float redm[2][5][16];   // [parity][row][wave]
    __shared__ __align__(16) float reds[5][16];
    __shared__ float redb[16];
    int b = blockIdx.x, t = threadIdx.x;
    int w = t >> 6, lane = t & 63;
    const float* Lb = logits + (size_t)b * 5 * 4096;
    float lk2[5][4], ek[5][4];
#pragma unroll
    for (int n = 0; n < 5; n++)
#pragma unroll
        for (int k = 0; k < 4; k++){
            float lv = (Lb[n*4096 + t + k*1024] / 0.05f) * LOG2E;  // log2 K
            lk2[n][k] = lv;
            ek[n][k] = exp2f(lv);
        }
    const float mu_lin  = 0.2f + 1e-8f;
    const float nu_lin  = 1.0f/4096.0f + 1e-8f;
    const float thr     = 1.00005e-4f;   // e^TOL - 1

    float vv[4]  = {1.f, 1.f, 1.f, 1.f};
    float en_prev[5] = {1.f, 1.f, 1.f, 1.f, 1.f};
    float en[5];
    float diff = 1e30f;
    int par = 0;

    for (int it = 0; it < 100; ++it){
        if (diff < 0.f) break;        // slack<0 <=> converged
        float gs[5];
#pragma unroll
        for (int n = 0; n < 5; n++)
            gs[n] = ek[n][0]*vv[0] + ek[n][1]*vv[1] + ek[n][2]*vv[2] + ek[n][3]*vv[3];
#pragma unroll
        for (int off = 1; off < 64; off <<= 1){
#pragma unroll
            for (int n = 0; n < 5; n++) gs[n] += __shfl_xor(gs[n], off);
        }
        if (lane == 0){
#pragma unroll
            for (int n = 0; n < 5; n++) redm[par][n][w] = gs[n];
        }
        __syncthreads();
        float slack = -1.f;
#pragma unroll
        for (int n = 0; n < 5; n++){
            const float4* rp = (const float4*)redm[par][n];
            float4 A4 = rp[0], B4 = rp[1], C4 = rp[2], D4 = rp[3];
            float s = (((A4.x+A4.y)+(A4.z+A4.w)) + ((B4.x+B4.y)+(B4.z+B4.w)))
                    + (((C4.x+C4.y)+(C4.z+C4.w)) + ((D4.x+D4.y)+(D4.z+D4.w)));
            float e = mu_lin / s;
            slack = fmaxf(slack, fabsf(e - en_prev[n]) - thr * en_prev[n]);
            en_prev[n] = e;
            en[n] = e;
        }
        diff = slack;
#pragma unroll
        for (int k = 0; k < 4; k++){
            float cs = ek[0][k]*en[0] + ek[1][k]*en[1] + ek[2][k]*en[2]
                     + ek[3][k]*en[3] + ek[4][k]*en[4];
            vv[k] = nu_lin / cs;
        }
        par ^= 1;
    }
    __syncthreads();

    // --- softmax row stats of raw logits (base-2): lraw2 = lk2 * EPS ---
    float tm[5];
#pragma unroll
    for (int n = 0; n < 5; n++){
        float l0 = lk2[n][0]*0.05f, l1 = lk2[n][1]*0.05f;
        float l2 = lk2[n][2]*0.05f, l3 = lk2[n][3]*0.05f;
        tm[n] = fmaxf(fmaxf(l0, l1), fmaxf(l2, l3));
    }
#pragma unroll
    for (int off = 1; off < 64; off <<= 1){
#pragma unroll
        for (int n = 0; n < 5; n++) tm[n] = fmaxf(tm[n], __shfl_xor(tm[n], off));
    }
    if (lane == 0){
#pragma unroll
        for (int n = 0; n < 5; n++) redm[0][n][w] = tm[n];
    }
    __syncthreads();
    float mx5[5];
#pragma unroll
    for (int n = 0; n < 5; n++){
        const float4* rp = (const float4*)redm[0][n];
        float4 A4 = rp[0], B4 = rp[1], C4 = rp[2], D4 = rp[3];
        float gm = fmaxf(fmaxf(fmaxf(A4.x,A4.y), fmaxf(A4.z,A4.w)),
                         fmaxf(fmaxf(B4.x,B4.y), fmaxf(B4.z,B4.w)));
        gm = fmaxf(gm, fmaxf(fmaxf(fmaxf(C4.x,C4.y), fmaxf(C4.z,C4.w)),
                             fmaxf(fmaxf(D4.x,D4.y), fmaxf(D4.z,D4.w))));
        mx5[n] = gm;
    }
    float pz[5];
#pragma unroll
    for (int n = 0; n < 5; n++){
        pz[n] = exp2f(lk2[n][0]*0.05f - mx5[n]) + exp2f(lk2[n][1]*0.05f - mx5[n])
              + exp2f(lk2[n][2]*0.05f - mx5[n]) + exp2f(lk2[n][3]*0.05f - mx5[n]);
    }
#pragma unroll
    for (int off = 1; off < 64; off <<= 1){
#pragma unroll
        for (int n = 0; n < 5; n++) pz[n] += __shfl_xor(pz[n], off);
    }
    if (lane == 0){
#pragma unroll
        for (int n = 0; n < 5; n++) reds[n][w] = pz[n];
    }
    __syncthreads();
    float iz5[5];
#pragma unroll
    for (int n = 0; n < 5; n++){
        const float4* rp = (const float4*)reds[n];
        float4 A4 = rp[0], B4 = rp[1], C4 = rp[2], D4 = rp[3];
        float z = (((A4.x+A4.y)+(A4.z+A4.w)) + ((B4.x+B4.y)+(B4.z+B4.w)))
                + (((C4.x+C4.y)+(C4.z+C4.w)) + ((D4.x+D4.y)+(D4.z+D4.w)));
        iz5[n] = 1.0f / z;
    }
    // --- BCE(T, M), T linear ---
    float acc = 0.f;
#pragma unroll
    for (int n = 0; n < 5; n++){
#pragma unroll
        for (int k = 0; k < 4; k++){
            float Mv = exp2f(lk2[n][k]*0.05f - mx5[n]) * iz5[n];
            float Mc = fminf(fmaxf(Mv, 1e-6f), 1.0f - 1e-6f);
            float T  = fminf(en[n] * ek[n][k] * vv[k], 1.0f);
            acc -= (T * log2f(Mc) + (1.0f - T) * log2f(1.0f - Mc)) * LN2;
        }
    }
    acc = warpReduceSum(acc);
    if (lane == 0) redb[w] = acc;
    __syncthreads();
    if (t == 0){
        float s = 0.f;
        for (int i = 0; i < 16; i++) s += redb[i];
        partial[b] = s;
    }
}

// ---------------------------------------------------------------------------
// K6: epilogue, one block per (b,n) row. 80 blocks x 512 threads.
// Block 0 also reduces the 16 sinkhorn partials into out[20480].
// ---------------------------------------------------------------------------
__global__ __launch_bounds__(512) void k_epilogue(
    const float* __restrict__ A, const float* __restrict__ P1,
    const float* __restrict__ wvw, const float* __restrict__ wvb,
    const float* __restrict__ clns, const float* __restrict__ clnb,
    const float* __restrict__ w1, const float* __restrict__ b1,
    const float* __restrict__ w2, const float* __restrict__ b2,
    const float* __restrict__ flns, const float* __restrict__ flnb,
    const float* __restrict__ sink_part,
    float* __restrict__ out)
{
    __shared__ float Ar[256], P1r[256], P2[256], hl[512], parts[2][256], s8[8];
    int bn = blockIdx.x;
    int n = bn % 5;
    int t = threadIdx.x;
    if (bn == 0 && t == 0){
        float s = 0.f;
        for (int i = 0; i < 16; i++) s += sink_part[i];
        out[20480] = s * (1.0f / (16.0f * 5.0f * 4096.0f));
    }
    if (t < 256){ Ar[t] = A[(size_t)bn*256 + t]; P1r[t] = P1[n*256 + t]; }
    __syncthreads();
    int c = t & 255, p = t >> 8;
    {
        float acc = 0.f;
        const float* wp = wvw + (size_t)(p*128)*256 + c;
#pragma unroll 16
        for (int k = 0; k < 128; k++) acc += Ar[p*128 + k] * wp[(size_t)k*256];
        parts[p][c] = acc;
    }
    __syncthreads();
    float x = 0.f;
    if (t < 256) x = P1r[t] + parts[0][t] + parts[1][t] + wvb[t];
    float sum  = blockSum512((t < 256) ? x : 0.f, s8);
    float mean = sum * (1.0f/256.0f);
    float d    = x - mean;
    float sq   = blockSum512((t < 256) ? d*d : 0.f, s8);
    float rstd = rsqrtf(sq * (1.0f/256.0f) + 1e-5f);
    float p2v = 0.f;
    if (t < 256){
        p2v = d * rstd * clns[t] + clnb[t];
        P2[t] = p2v;
    }
    __syncthreads();
    {
        float a = b1[t];
        const float* wp = w1 + t;
#pragma unroll 16
        for (int k = 0; k < 256; k++) a += P2[k] * wp[(size_t)k*512];
        hl[t] = 0.5f * a * (1.0f + erff(a * 0.70710678118654752f));
    }
    __syncthreads();
    {
        float acc = 0.f;
        const float* wp = w2 + (size_t)(p*256)*256 + c;
#pragma unroll 16
        for (int k = 0; k < 256; k++) acc += hl[p*256 + k] * wp[(size_t)k*256];
        parts[p][c] = acc;
    }
    __syncthreads();
    float x2 = 0.f;
    if (t < 256) x2 = P2[t] + parts[0][t] + parts[1][t] + b2[t];
    float sum2  = blockSum512((t < 256) ? x2 : 0.f, s8);
    float mean2 = sum2 * (1.0f/256.0f);
    float d2    = x2 - mean2;
    float sq2   = blockSum512((t < 256) ? d2*d2 : 0.f, s8);
    float rstd2 = rsqrtf(sq2 * (1.0f/256.0f) + 1e-5f);
    if (t < 256) out[(size_t)bn*256 + t] = d2 * rstd2 * flns[t] + flnb[t];
}

// ---------------------------------------------------------------------------
extern "C" void kernel_launch(void* const* d_in, const int* in_sizes, int n_in,
                              void* d_out, int out_size, void* d_ws, size_t ws_size,
                              hipStream_t stream)
{
    const float* Fd      = (const float*)d_in[0];
    const float* prompts = (const float*)d_in[1];
    const float* sa_q_w  = (const float*)d_in[2];
    const float* sa_q_b  = (const float*)d_in[3];
    const float* sa_k_w  = (const float*)d_in[4];
    const float* sa_k_b  = (const float*)d_in[5];
    const float* sa_v_w  = (const float*)d_in[6];
    const float* sa_v_b  = (const float*)d_in[7];
    const float* sa_ln_s = (const float*)d_in[8];
    const float* sa_ln_b = (const float*)d_in[9];
    const float* wq_w    = (const float*)d_in[10];
    const float* wq_b    = (const float*)d_in[11];
    const float* wk_w    = (const float*)d_in[12];
    const float* wk_b    = (const float*)d_in[13];
    const float* wv_w    = (const float*)d_in[14];
    const float* wv_b    = (const float*)d_in[15];
    const float* ca_ln_s = (const float*)d_in[16];
    const float* ca_ln_b = (const float*)d_in[17];
    const float* ffn_w1  = (const float*)d_in[18];
    const float* ffn_b1  = (const float*)d_in[19];
    const float* ffn_w2  = (const float*)d_in[20];
    const float* ffn_b2  = (const float*)d_in[21];
    const float* ffn_ln_s= (const float*)d_in[22];
    const float* ffn_ln_b= (const float*)d_in[23];

    float* out = (float*)d_out;
    float* ws  = (float*)d_ws;

    // workspace layout (floats)
    float* P1     = ws;            // 1280
    float* qkb    = ws + 1536;     // 5
    float* QKV    = ws + 2048;     // 3840
    float* Qc     = ws + 6144;     // 1280
    float* qkg    = ws + 8192;     // 1280
    float* spart  = ws + 9472;     // 16
    float* logits = ws + 73728;    // 327680
    float* Amat   = ws + 401408;   // 20480

    k_qkv<<<12, 256, 0, stream>>>(prompts, sa_q_w, sa_q_b, sa_k_w, sa_k_b,
                                  sa_v_w, sa_v_b, QKV);
    k_attn_qc<<<5, 256, 0, stream>>>(QKV, prompts, sa_ln_s, sa_ln_b,
                                     wq_w, wq_b, P1, Qc);
    k_qk2<<<dim3(16, 5), 256, 0, stream>>>(Qc, wk_w, wk_b, qkg, qkb);
    k_logits<<<dim3(16, 16), 1024, 0, stream>>>(Fd, qkg, qkb, logits);
    k_A<<<dim3(16, 16), 1024, 0, stream>>>(Fd, logits, Amat);
    k_sinkhorn<<<16, 1024, 0, stream>>>(logits, spart);
    k_epilogue<<<80, 512, 0, stream>>>(Amat, P1, wv_w, wv_b, ca_ln_s, ca_ln_b,
                                       ffn_w1, ffn_b1, ffn_w2, ffn_b2,
                                       ffn_ln_s, ffn_ln_b, spart, out);
}

// Round 9
// 218.748 us; speedup vs baseline: 2.2285x; 1.1295x over previous
//
#include <hip/hip_runtime.h>
#include <hip/hip_fp16.h>
#include <math.h>

#define LOG2E 1.44269504088896340f
#define LN2   0.69314718055994531f

__device__ __forceinline__ float fastrcp(float x){ return __builtin_amdgcn_rcpf(x); }

__device__ __forceinline__ float warpReduceSum(float v){
#pragma unroll
    for (int off = 32; off > 0; off >>= 1) v += __shfl_down(v, off);
    return v;
}
__device__ __forceinline__ float warpReduceMax(float v){
#pragma unroll
    for (int off = 32; off > 0; off >>= 1) v = fmaxf(v, __shfl_down(v, off));
    return v;
}

// block of 256 threads (4 waves)
__device__ float blockSum256(float v, float* s4){
    v = warpReduceSum(v);
    int w = threadIdx.x >> 6;
    __syncthreads();
    if ((threadIdx.x & 63) == 0) s4[w] = v;
    __syncthreads();
    return s4[0] + s4[1] + s4[2] + s4[3];
}
// block of 512 threads (8 waves)
__device__ float blockSum512(float v, float* s8){
    v = warpReduceSum(v);
    int w = threadIdx.x >> 6;
    __syncthreads();
    if ((threadIdx.x & 63) == 0) s8[w] = v;
    __syncthreads();
    float s = 0.f;
#pragma unroll
    for (int i = 0; i < 8; i++) s += s8[i];
    return s;
}

// ---------------------------------------------------------------------------
// K1: QKV projections of prompts. grid 12 blocks (3 mat x 4 col-chunks).
// ---------------------------------------------------------------------------
__global__ __launch_bounds__(256) void k_qkv(
    const float* __restrict__ prompts,
    const float* __restrict__ qw, const float* __restrict__ qb,
    const float* __restrict__ kw, const float* __restrict__ kb,
    const float* __restrict__ vw, const float* __restrict__ vb,
    float* __restrict__ QKV)
{
    __shared__ float Pl[1280];
    __shared__ float parts[4][5][64];
    int t = threadIdx.x;
    int mat = blockIdx.x >> 2, chunk = blockIdx.x & 3;
    for (int i = t; i < 1280; i += 256) Pl[i] = prompts[i];
    const float* W  = (mat == 0) ? qw : (mat == 1) ? kw : vw;
    const float* Bv = (mat == 0) ? qb : (mat == 1) ? kb : vb;
    int cl = t & 63, p = t >> 6;
    int col = chunk*64 + cl;
    __syncthreads();
    float acc[5] = {0,0,0,0,0};
    const float* wp = W + (size_t)(p*64)*256 + col;
#pragma unroll 8
    for (int c = 0; c < 64; c++){
        float wv = wp[(size_t)c*256];
#pragma unroll
        for (int n = 0; n < 5; n++) acc[n] += Pl[n*256 + p*64 + c] * wv;
    }
#pragma unroll
    for (int n = 0; n < 5; n++) parts[p][n][cl] = acc[n];
    __syncthreads();
    for (int i = t; i < 320; i += 256){
        int n = i >> 6, c2 = i & 63;
        float s = parts[0][n][c2] + parts[1][n][c2] + parts[2][n][c2] + parts[3][n][c2]
                + Bv[chunk*64 + c2];
        QKV[mat*1280 + n*256 + chunk*64 + c2] = s;
    }
}

// ---------------------------------------------------------------------------
// K2: prompt self-attention + LN -> P1, fused with Qc. grid 5 x 256.
// ---------------------------------------------------------------------------
__global__ __launch_bounds__(256) void k_attn_qc(
    const float* __restrict__ QKV, const float* __restrict__ prompts,
    const float* __restrict__ lns, const float* __restrict__ lnb,
    const float* __restrict__ wqw, const float* __restrict__ wqb,
    float* __restrict__ P1g, float* __restrict__ Qcg)
{
    __shared__ float Pl[1280], Ql[1280], Kl[1280], Vl[1280], Sl[25], s4[4];
    int t = threadIdx.x;
    for (int i = t; i < 1280; i += 256){
        Pl[i] = prompts[i];
        Ql[i] = QKV[i];
        Kl[i] = QKV[1280 + i];
        Vl[i] = QKV[2560 + i];
    }
    __syncthreads();
    if (t < 25){
        int n = t / 5, m = t % 5;
        float s = 0.f;
        for (int c = 0; c < 256; c++) s += Ql[n*256 + c] * Kl[m*256 + c];
        Sl[t] = s * 0.0625f;
    }
    __syncthreads();
    if (t < 5){
        float mx = -1e30f;
        for (int m = 0; m < 5; m++) mx = fmaxf(mx, Sl[t*5 + m]);
        float e[5], sm = 0.f;
        for (int m = 0; m < 5; m++){ e[m] = expf(Sl[t*5 + m] - mx); sm += e[m]; }
        for (int m = 0; m < 5; m++) Sl[t*5 + m] = e[m] / sm;
    }
    __syncthreads();
    float x[5];
#pragma unroll
    for (int n = 0; n < 5; n++){
        float s = 0.f;
        for (int m = 0; m < 5; m++) s += Sl[n*5 + m] * Vl[m*256 + t];
        x[n] = Pl[n*256 + t] + s;
    }
#pragma unroll
    for (int n = 0; n < 5; n++){
        float sum  = blockSum256(x[n], s4);
        float mean = sum * (1.0f/256.0f);
        float d    = x[n] - mean;
        float sq   = blockSum256(d*d, s4);
        float rstd = rsqrtf(sq * (1.0f/256.0f) + 1e-5f);
        float y = d * rstd * lns[t] + lnb[t];
        Pl[n*256 + t] = y;
        if (blockIdx.x == 0) P1g[n*256 + t] = y;
    }
    __syncthreads();
    int n = blockIdx.x;
    float acc = wqb[t];
    const float* wp = wqw + t;
#pragma unroll 16
    for (int d = 0; d < 256; d++) acc += Pl[n*256 + d] * wp[(size_t)d*256];
    Qcg[n*256 + t] = acc;
}

// ---------------------------------------------------------------------------
// K2c: qk[n][c] = sum_d Qc[n][d]*wk_w[c][d];  qkb[n] = Qc[n].wk_b.
// grid (16,5) x 256 threads.
// ---------------------------------------------------------------------------
__global__ __launch_bounds__(256) void k_qk2(
    const float* __restrict__ Qc, const float* __restrict__ wkw,
    const float* __restrict__ wkb,
    float* __restrict__ qkg, float* __restrict__ qkbg)
{
    __shared__ float Qr[256], s4[4];
    int n = blockIdx.y, t = threadIdx.x;
    int w = t >> 6, lane = t & 63;
    Qr[t] = Qc[n*256 + t];
    __syncthreads();
#pragma unroll
    for (int i = 0; i < 4; i++){
        int c = blockIdx.x*16 + w*4 + i;
        const float* kp = wkw + (size_t)c*256;
        float acc = Qr[lane]       * kp[lane]
                  + Qr[lane + 64]  * kp[lane + 64]
                  + Qr[lane + 128] * kp[lane + 128]
                  + Qr[lane + 192] * kp[lane + 192];
#pragma unroll
        for (int off = 1; off < 64; off <<= 1) acc += __shfl_xor(acc, off);
        if (lane == 0) qkg[n*256 + c] = acc;
    }
    if (blockIdx.x == 0){
        float pu = blockSum256(Qr[t] * wkb[t], s4);
        if (t == 0) qkbg[n] = pu;
    }
}

// ---------------------------------------------------------------------------
// K3: logits[b,n,m] = scale*(qk[n,:].Fd[b,:,m] + qkb[n]).
// grid (16,16) x 1024 threads: 4-way c-split for TLP on the cold Fd stream.
// ---------------------------------------------------------------------------
__global__ __launch_bounds__(1024) void k_logits(
    const float* __restrict__ Fd, const float* __restrict__ qkg,
    const float* __restrict__ qkbg, float* __restrict__ logits)
{
    __shared__ float qk[1280];
    __shared__ float qb5[5];
    __shared__ float parts[4][5][256];
    int t = threadIdx.x;
    for (int i = t; i < 1280; i += 1024) qk[i] = qkg[i];
    if (t < 5) qb5[t] = qkbg[t];
    __syncthreads();
    int b = blockIdx.y;
    int p = t >> 8, ml = t & 255;
    int m = blockIdx.x * 256 + ml;
    const float* fp = Fd + ((size_t)(b*256 + p*64)) * 4096 + m;
    float a0 = 0.f, a1 = 0.f, a2 = 0.f, a3 = 0.f, a4 = 0.f;
#pragma unroll 16
    for (int c = 0; c < 64; c++){
        float f = fp[(size_t)c * 4096];
        a0 += qk[          p*64 + c] * f;
        a1 += qk[256  +    p*64 + c] * f;
        a2 += qk[512  +    p*64 + c] * f;
        a3 += qk[768  +    p*64 + c] * f;
        a4 += qk[1024 +    p*64 + c] * f;
    }
    parts[p][0][ml] = a0; parts[p][1][ml] = a1; parts[p][2][ml] = a2;
    parts[p][3][ml] = a3; parts[p][4][ml] = a4;
    __syncthreads();
    for (int i = t; i < 1280; i += 1024){
        int n = i >> 8, mm = i & 255;
        float s = parts[0][n][mm] + parts[1][n][mm] + parts[2][n][mm] + parts[3][n][mm]
                + qb5[n];
        logits[((size_t)(b*5) + n)*4096 + blockIdx.x*256 + mm] = s * 0.0625f;
    }
}

// ---------------------------------------------------------------------------
// K4: merged A + Sinkhorn. 272 blocks x 1024 threads.
// Blocks 0..15: per-batch Sinkhorn+BCE (dispatched first -> runs concurrent
// with the A blocks that stream Fd).  Blocks 16..271: A computation.
// ---------------------------------------------------------------------------
__global__ __launch_bounds__(1024) void k_A_sink(
    const float* __restrict__ Fd, const float* __restrict__ logits,
    float* __restrict__ A, float* __restrict__ partial)
{
    __shared__ __align__(16) __half Ml[5*4096];   // A path (40KB)
    __shared__ float red[80];                     // A path
    __shared__ __align__(16) float redm[2][5][16];// sink path
    __shared__ float redb[16];                    // sink path
    int t = threadIdx.x;
    int w = t >> 6, lane = t & 63;

    if (blockIdx.x < 16){
        // ================= Sinkhorn path =================
        int b = blockIdx.x;
        const float* Lb = logits + (size_t)b * 5 * 4096;
        float lk2[5][4], ek[5][4];
#pragma unroll
        for (int n = 0; n < 5; n++)
#pragma unroll
            for (int k = 0; k < 4; k++){
                float lv = (Lb[n*4096 + t + k*1024] * 20.0f) * LOG2E;  // log2 K
                lk2[n][k] = lv;
                ek[n][k] = exp2f(lv);
            }
        const float mu_lin  = 0.2f + 1e-8f;
        const float nu_lin  = 1.0f/4096.0f + 1e-8f;
        const float thr     = 1.00005e-4f;

        float vv[4]  = {1.f, 1.f, 1.f, 1.f};
        float en_prev[5] = {1.f, 1.f, 1.f, 1.f, 1.f};
        float en[5];
        float diff = 1e30f;
        int par = 0;

        for (int it = 0; it < 100; ++it){
            if (diff < 0.f) break;
            float gs[5];
#pragma unroll
            for (int n = 0; n < 5; n++)
                gs[n] = ek[n][0]*vv[0] + ek[n][1]*vv[1] + ek[n][2]*vv[2] + ek[n][3]*vv[3];
#pragma unroll
            for (int off = 1; off < 64; off <<= 1){
#pragma unroll
                for (int n = 0; n < 5; n++) gs[n] += __shfl_xor(gs[n], off);
            }
            if (lane == 0){
#pragma unroll
                for (int n = 0; n < 5; n++) redm[par][n][w] = gs[n];
            }
            __syncthreads();
            // 16-lane-group combine: lane g reads wave-g partial, 4-stage reduce
            float s5[5];
            int g = lane & 15;
#pragma unroll
            for (int n = 0; n < 5; n++) s5[n] = redm[par][n][g];
#pragma unroll
            for (int off = 1; off < 16; off <<= 1){
#pragma unroll
                for (int n = 0; n < 5; n++) s5[n] += __shfl_xor(s5[n], off);
            }
            float slack = -1.f;
#pragma unroll
            for (int n = 0; n < 5; n++){
                float e = mu_lin * fastrcp(s5[n]);
                slack = fmaxf(slack, fabsf(e - en_prev[n]) - thr * en_prev[n]);
                en_prev[n] = e;
                en[n] = e;
            }
            diff = slack;
#pragma unroll
            for (int k = 0; k < 4; k++){
                float cs = ek[0][k]*en[0] + ek[1][k]*en[1] + ek[2][k]*en[2]
                         + ek[3][k]*en[3] + ek[4][k]*en[4];
                vv[k] = nu_lin * fastrcp(cs);
            }
            par ^= 1;
        }
        __syncthreads();

        // softmax row stats of raw logits (base-2): lraw2 = lk2 * EPS
        float tm[5];
#pragma unroll
        for (int n = 0; n < 5; n++){
            float l0 = lk2[n][0]*0.05f, l1 = lk2[n][1]*0.05f;
            float l2 = lk2[n][2]*0.05f, l3 = lk2[n][3]*0.05f;
            tm[n] = fmaxf(fmaxf(l0, l1), fmaxf(l2, l3));
        }
#pragma unroll
        for (int off = 1; off < 64; off <<= 1){
#pragma unroll
            for (int n = 0; n < 5; n++) tm[n] = fmaxf(tm[n], __shfl_xor(tm[n], off));
        }
        if (lane == 0){
#pragma unroll
            for (int n = 0; n < 5; n++) redm[0][n][w] = tm[n];
        }
        __syncthreads();
        float mx5[5];
        {
            int g = lane & 15;
#pragma unroll
            for (int n = 0; n < 5; n++) mx5[n] = redm[0][n][g];
#pragma unroll
            for (int off = 1; off < 16; off <<= 1){
#pragma unroll
                for (int n = 0; n < 5; n++) mx5[n] = fmaxf(mx5[n], __shfl_xor(mx5[n], off));
            }
        }
        float pz[5];
#pragma unroll
        for (int n = 0; n < 5; n++){
            pz[n] = exp2f(lk2[n][0]*0.05f - mx5[n]) + exp2f(lk2[n][1]*0.05f - mx5[n])
                  + exp2f(lk2[n][2]*0.05f - mx5[n]) + exp2f(lk2[n][3]*0.05f - mx5[n]);
        }
#pragma unroll
        for (int off = 1; off < 64; off <<= 1){
#pragma unroll
            for (int n = 0; n < 5; n++) pz[n] += __shfl_xor(pz[n], off);
        }
        __syncthreads();
        if (lane == 0){
#pragma unroll
            for (int n = 0; n < 5; n++) redm[1][n][w] = pz[n];
        }
        __syncthreads();
        float iz5[5];
        {
            int g = lane & 15;
#pragma unroll
            for (int n = 0; n < 5; n++) iz5[n] = redm[1][n][g];
#pragma unroll
            for (int off = 1; off < 16; off <<= 1){
#pragma unroll
                for (int n = 0; n < 5; n++) iz5[n] += __shfl_xor(iz5[n], off);
            }
#pragma unroll
            for (int n = 0; n < 5; n++) iz5[n] = fastrcp(iz5[n]);
        }
        // BCE(T, M), T linear
        float acc = 0.f;
#pragma unroll
        for (int n = 0; n < 5; n++){
#pragma unroll
            for (int k = 0; k < 4; k++){
                float Mv = exp2f(lk2[n][k]*0.05f - mx5[n]) * iz5[n];
                float Mc = fminf(fmaxf(Mv, 1e-6f), 1.0f - 1e-6f);
                float T  = fminf(en[n] * ek[n][k] * vv[k], 1.0f);
                acc -= (T * log2f(Mc) + (1.0f - T) * log2f(1.0f - Mc)) * LN2;
            }
        }
        acc = warpReduceSum(acc);
        if (lane == 0) redb[w] = acc;
        __syncthreads();
        if (t == 0){
            float s = 0.f;
            for (int i = 0; i < 16; i++) s += redb[i];
            partial[b] = s;
        }
        return;
    }

    // ================= A path =================
    int bid = blockIdx.x - 16;
    int b = bid >> 4, cc = bid & 15;
    const float* Lb = logits + (size_t)(b*5) * 4096;
    float ll[5][4];
#pragma unroll
    for (int n = 0; n < 5; n++)
#pragma unroll
        for (int k = 0; k < 4; k++)
            ll[n][k] = Lb[n*4096 + t + k*1024];
#pragma unroll
    for (int n = 0; n < 5; n++){
        float tm = fmaxf(fmaxf(ll[n][0], ll[n][1]), fmaxf(ll[n][2], ll[n][3]));
        tm = warpReduceMax(tm);
        if (lane == 0) red[w*5 + n] = tm;
    }
    __syncthreads();
    float mx[5];
#pragma unroll
    for (int n = 0; n < 5; n++){
        float gm = -1e30f;
        for (int i = 0; i < 16; i++) gm = fmaxf(gm, red[i*5 + n]);
        mx[n] = gm;
    }
    __syncthreads();
    float e[5][4];
#pragma unroll
    for (int n = 0; n < 5; n++){
        float ps = 0.f;
#pragma unroll
        for (int k = 0; k < 4; k++){ e[n][k] = expf(ll[n][k] - mx[n]); ps += e[n][k]; }
        ps = warpReduceSum(ps);
        if (lane == 0) red[w*5 + n] = ps;
    }
    __syncthreads();
#pragma unroll
    for (int n = 0; n < 5; n++){
        float z = 0.f;
        for (int i = 0; i < 16; i++) z += red[i*5 + n];
        float inv = 1.0f / z;
#pragma unroll
        for (int k = 0; k < 4; k++)
            Ml[n*4096 + t + k*1024] = __float2half(e[n][k] * inv);
    }
    __syncthreads();
    int c = cc*16 + w;
    const float* fp = Fd + ((size_t)(b*256 + c)) * 4096;
    float4 a4[5];
#pragma unroll
    for (int n = 0; n < 5; n++) a4[n] = make_float4(0.f, 0.f, 0.f, 0.f);
#pragma unroll 4
    for (int it = 0; it < 16; it++){
        int m4 = it*256 + (lane << 2);
        float4 f = *(const float4*)(fp + m4);
#pragma unroll
        for (int n = 0; n < 5; n++){
            const __half2* mp = (const __half2*)(Ml + n*4096 + m4);
            float2 m0 = __half22float2(mp[0]);
            float2 m1 = __half22float2(mp[1]);
            a4[n].x += m0.x * f.x; a4[n].y += m0.y * f.y;
            a4[n].z += m1.x * f.z; a4[n].w += m1.y * f.w;
        }
    }
#pragma unroll
    for (int n = 0; n < 5; n++){
        float s = a4[n].x + a4[n].y + a4[n].z + a4[n].w;
        s = warpReduceSum(s);
        if (lane == 0) A[(size_t)(b*5 + n)*256 + c] = s;
    }
}

// ---------------------------------------------------------------------------
// K6: epilogue, one block per (b,n) row. 80 blocks x 512 threads.
// Block 0 also reduces the 16 sinkhorn partials into out[20480].
// ---------------------------------------------------------------------------
__global__ __launch_bounds__(512) void k_epilogue(
    const float* __restrict__ A, const float* __restrict__ P1,
    const float* __restrict__ wvw, const float* __restrict__ wvb,
    const float* __restrict__ clns, const float* __restrict__ clnb,
    const float* __restrict__ w1, const float* __restrict__ b1,
    const float* __restrict__ w2, const float* __restrict__ b2,
    const float* __restrict__ flns, const float* __restrict__ flnb,
    const float* __restrict__ sink_part,
    float* __restrict__ out)
{
    __shared__ float Ar[256], P1r[256], P2[256], hl[512], parts[2][256], s8[8];
    int bn = blockIdx.x;
    int n = bn % 5;
    int t = threadIdx.x;
    if (bn == 0 && t == 0){
        float s = 0.f;
        for (int i = 0; i < 16; i++) s += sink_part[i];
        out[20480] = s * (1.0f / (16.0f * 5.0f * 4096.0f));
    }
    if (t < 256){ Ar[t] = A[(size_t)bn*256 + t]; P1r[t] = P1[n*256 + t]; }
    __syncthreads();
    int c = t & 255, p = t >> 8;
    {
        float acc = 0.f;
        const float* wp = wvw + (size_t)(p*128)*256 + c;
#pragma unroll 16
        for (int k = 0; k < 128; k++) acc += Ar[p*128 + k] * wp[(size_t)k*256];
        parts[p][c] = acc;
    }
    __syncthreads();
    float x = 0.f;
    if (t < 256) x = P1r[t] + parts[0][t] + parts[1][t] + wvb[t];
    float sum  = blockSum512((t < 256) ? x : 0.f, s8);
    float mean = sum * (1.0f/256.0f);
    float d    = x - mean;
    float sq   = blockSum512((t < 256) ? d*d : 0.f, s8);
    float rstd = rsqrtf(sq * (1.0f/256.0f) + 1e-5f);
    float p2v = 0.f;
    if (t < 256){
        p2v = d * rstd * clns[t] + clnb[t];
        P2[t] = p2v;
    }
    __syncthreads();
    {
        float a = b1[t];
        const float* wp = w1 + t;
#pragma unroll 16
        for (int k = 0; k < 256; k++) a += P2[k] * wp[(size_t)k*512];
        hl[t] = 0.5f * a * (1.0f + erff(a * 0.70710678118654752f));
    }
    __syncthreads();
    {
        float acc = 0.f;
        const float* wp = w2 + (size_t)(p*256)*256 + c;
#pragma unroll 16
        for (int k = 0; k < 256; k++) acc += hl[p*256 + k] * wp[(size_t)k*256];
        parts[p][c] = acc;
    }
    __syncthreads();
    float x2 = 0.f;
    if (t < 256) x2 = P2[t] + parts[0][t] + parts[1][t] + b2[t];
    float sum2  = blockSum512((t < 256) ? x2 : 0.f, s8);
    float mean2 = sum2 * (1.0f/256.0f);
    float d2    = x2 - mean2;
    float sq2   = blockSum512((t < 256) ? d2*d2 : 0.f, s8);
    float rstd2 = rsqrtf(sq2 * (1.0f/256.0f) + 1e-5f);
    if (t < 256) out[(size_t)bn*256 + t] = d2 * rstd2 * flns[t] + flnb[t];
}

// ---------------------------------------------------------------------------
extern "C" void kernel_launch(void* const* d_in, const int* in_sizes, int n_in,
                              void* d_out, int out_size, void* d_ws, size_t ws_size,
                              hipStream_t stream)
{
    const float* Fd      = (const float*)d_in[0];
    const float* prompts = (const float*)d_in[1];
    const float* sa_q_w  = (const float*)d_in[2];
    const float* sa_q_b  = (const float*)d_in[3];
    const float* sa_k_w  = (const float*)d_in[4];
    const float* sa_k_b  = (const float*)d_in[5];
    const float* sa_v_w  = (const float*)d_in[6];
    const float* sa_v_b  = (const float*)d_in[7];
    const float* sa_ln_s = (const float*)d_in[8];
    const float* sa_ln_b = (const float*)d_in[9];
    const float* wq_w    = (const float*)d_in[10];
    const float* wq_b    = (const float*)d_in[11];
    const float* wk_w    = (const float*)d_in[12];
    const float* wk_b    = (const float*)d_in[13];
    const float* wv_w    = (const float*)d_in[14];
    const float* wv_b    = (const float*)d_in[15];
    const float* ca_ln_s = (const float*)d_in[16];
    const float* ca_ln_b = (const float*)d_in[17];
    const float* ffn_w1  = (const float*)d_in[18];
    const float* ffn_b1  = (const float*)d_in[19];
    const float* ffn_w2  = (const float*)d_in[20];
    const float* ffn_b2  = (const float*)d_in[21];
    const float* ffn_ln_s= (const float*)d_in[22];
    const float* ffn_ln_b= (const float*)d_in[23];

    float* out = (float*)d_out;
    float* ws  = (float*)d_ws;

    // workspace layout (floats)
    float* P1     = ws;            // 1280
    float* qkb    = ws + 1536;     // 5
    float* QKV    = ws + 2048;     // 3840
    float* Qc     = ws + 6144;     // 1280
    float* qkg    = ws + 8192;     // 1280
    float* spart  = ws + 9472;     // 16
    float* logits = ws + 73728;    // 327680
    float* Amat   = ws + 401408;   // 20480

    k_qkv<<<12, 256, 0, stream>>>(prompts, sa_q_w, sa_q_b, sa_k_w, sa_k_b,
                                  sa_v_w, sa_v_b, QKV);
    k_attn_qc<<<5, 256, 0, stream>>>(QKV, prompts, sa_ln_s, sa_ln_b,
                                     wq_w, wq_b, P1, Qc);
    k_qk2<<<dim3(16, 5), 256, 0, stream>>>(Qc, wk_w, wk_b, qkg, qkb);
    k_logits<<<dim3(16, 16), 1024, 0, stream>>>(Fd, qkg, qkb, logits);
    k_A_sink<<<272, 1024, 0, stream>>>(Fd, logits, Amat, spart);
    k_epilogue<<<80, 512, 0, stream>>>(Amat, P1, wv_w, wv_b, ca_ln_s, ca_ln_b,
                                       ffn_w1, ffn_b1, ffn_w2, ffn_b2,
                                       ffn_ln_s, ffn_ln_b, spart, out);
}